// Round 22
// baseline (250.341 us; speedup 1.0000x reference)
//
#include <hip/hip_runtime.h>
#include <hip/hip_bf16.h>

typedef __hip_bfloat16 obf;
typedef __attribute__((ext_vector_type(8))) __bf16 bf16x8;
typedef __attribute__((ext_vector_type(4))) float f32x4;

#define DEVINL __device__ __forceinline__

DEVINL void gload_lds16(const void* g, void* l) {
  __builtin_amdgcn_global_load_lds((const __attribute__((address_space(1))) void*)g,
                                   (__attribute__((address_space(3))) void*)l,
                                   16, 0, 0);
}

// ---------------- f32 -> bf16 conversion (weights) ----------------
__global__ void __launch_bounds__(256) f2b_kernel(const float* __restrict__ in,
                                                  __bf16* __restrict__ out, int n8)
{
  const int i = blockIdx.x * 256 + threadIdx.x;
  if (i >= n8) return;
  const float4 a = ((const float4*)in)[i * 2];
  const float4 b = ((const float4*)in)[i * 2 + 1];
  bf16x8 o;
  o[0] = (__bf16)a.x; o[1] = (__bf16)a.y; o[2] = (__bf16)a.z; o[3] = (__bf16)a.w;
  o[4] = (__bf16)b.x; o[5] = (__bf16)b.y; o[6] = (__bf16)b.z; o[7] = (__bf16)b.w;
  ((bf16x8*)out)[i] = o;
}

// ------- merged LayerNorm + up to two f2b segments (independent, one dispatch) -------
// blocks [0, nln): LN rows; [nln, nln+nb1): f2b win1; [nln+nb1, ...): f2b win2.
__global__ void __launch_bounds__(256) ln_f2b2_kernel(
    const float* __restrict__ xin, const float* __restrict__ g, const float* __restrict__ b,
    obf* __restrict__ lnout,
    const float* __restrict__ win1, __bf16* __restrict__ wout1, int n8_1, int nb1,
    const float* __restrict__ win2, __bf16* __restrict__ wout2, int n8_2,
    int nln)
{
  __shared__ float red[8];
  const int t = threadIdx.x;
  const int bx = blockIdx.x;
  if (bx < nln) {
    const int row = bx;
    const int lane = t & 63, w = t >> 6;
    float4 f = ((const float4*)xin)[(size_t)row * 256 + t];
    float v[4] = { f.x, f.y, f.z, f.w };
    float s1 = v[0] + v[1] + v[2] + v[3];
    float s2 = v[0]*v[0] + v[1]*v[1] + v[2]*v[2] + v[3]*v[3];
    #pragma unroll
    for (int off = 32; off >= 1; off >>= 1) {
      s1 += __shfl_xor(s1, off);
      s2 += __shfl_xor(s2, off);
    }
    if (lane == 0) { red[w] = s1; red[4 + w] = s2; }
    __syncthreads();
    s1 = red[0] + red[1] + red[2] + red[3];
    s2 = red[4] + red[5] + red[6] + red[7];
    const float mu = s1 * (1.f / 1024.f);
    const float var = s2 * (1.f / 1024.f) - mu * mu;
    const float rs = rsqrtf(var + 1e-5f);
    const float4 gv = ((const float4*)g)[t];
    const float4 bv = ((const float4*)b)[t];
    obf* op = lnout + (size_t)row * 1024 + t * 4;
    op[0] = __float2bfloat16((v[0] - mu) * rs * gv.x + bv.x);
    op[1] = __float2bfloat16((v[1] - mu) * rs * gv.y + bv.y);
    op[2] = __float2bfloat16((v[2] - mu) * rs * gv.z + bv.z);
    op[3] = __float2bfloat16((v[3] - mu) * rs * gv.w + bv.w);
  } else if (bx < nln + nb1) {
    const int i = (bx - nln) * 256 + t;
    if (i >= n8_1) return;
    const float4 a = ((const float4*)win1)[i * 2];
    const float4 b2 = ((const float4*)win1)[i * 2 + 1];
    bf16x8 o;
    o[0] = (__bf16)a.x;  o[1] = (__bf16)a.y;  o[2] = (__bf16)a.z;  o[3] = (__bf16)a.w;
    o[4] = (__bf16)b2.x; o[5] = (__bf16)b2.y; o[6] = (__bf16)b2.z; o[7] = (__bf16)b2.w;
    ((bf16x8*)wout1)[i] = o;
  } else {
    const int i = (bx - nln - nb1) * 256 + t;
    if (i >= n8_2) return;
    const float4 a = ((const float4*)win2)[i * 2];
    const float4 b2 = ((const float4*)win2)[i * 2 + 1];
    bf16x8 o;
    o[0] = (__bf16)a.x;  o[1] = (__bf16)a.y;  o[2] = (__bf16)a.z;  o[3] = (__bf16)a.w;
    o[4] = (__bf16)b2.x; o[5] = (__bf16)b2.y; o[6] = (__bf16)b2.z; o[7] = (__bf16)b2.w;
    ((bf16x8*)wout2)[i] = o;
  }
}

// ---------------- GEMM 128-tile: C[M,N] = A[M,K] @ W[N,K]^T (+ epilogue) ----------------
// FINAL pinned form: single-buffer 2-barrier, 32KB LDS, ~3.4-4 blocks/CU.
// GELU epilogue: tanh form (validated r21, absmax unchanged).
enum { EPI_NONE = 0, EPI_BIAS_RES_F32OUT = 1, EPI_BIAS_GELU = 2, EPI_BIAS_RESF32_F32OUT = 3 };

template<int EPI, int NI>
__global__ void __launch_bounds__(256, 2) gemm_bt(
    const obf* __restrict__ A, const obf* __restrict__ Bw,
    void* __restrict__ Cout, const float* __restrict__ bias,
    const void* __restrict__ resid, int M, int N, int K)
{
  __shared__ __align__(16) char As[128 * 64 * 2];
  __shared__ __align__(16) char Bs[NI * 32 * 64 * 2];
  const int tid = threadIdx.x;
  const int lane = tid & 63;
  const int w = tid >> 6, wr = w >> 1, wc = w & 1;
  const int bm = blockIdx.y * 128, bn = blockIdx.x * (NI * 32);
  const size_t lda = (size_t)K * 2;

  f32x4 acc[4][NI];
  #pragma unroll
  for (int i = 0; i < 4; i++)
    #pragma unroll
    for (int j = 0; j < NI; j++) {
      acc[i][j][0] = 0.f; acc[i][j][1] = 0.f; acc[i][j][2] = 0.f; acc[i][j][3] = 0.f;
    }

  for (int k0 = 0; k0 < K; k0 += 64) {
    #pragma unroll
    for (int i = 0; i < 4; i++) {
      const int ci = tid + 256 * i;
      const int r = ci >> 3;
      const int gb = ((ci & 7) * 16) ^ ((r & 7) << 4);
      gload_lds16((const char*)A + (size_t)(bm + r) * lda + (size_t)k0 * 2 + gb, As + ci * 16);
    }
    #pragma unroll
    for (int i = 0; i < NI; i++) {
      const int ci = tid + 256 * i;
      const int r = ci >> 3;
      const int gb = ((ci & 7) * 16) ^ ((r & 7) << 4);
      gload_lds16((const char*)Bw + (size_t)(bn + r) * lda + (size_t)k0 * 2 + gb, Bs + ci * 16);
    }
    __syncthreads();

    bf16x8 af[4][2], bfr[NI][2];
    #pragma unroll
    for (int mi = 0; mi < 4; mi++) {
      const int r = wr * 64 + mi * 16 + (lane & 15);
      #pragma unroll
      for (int ks = 0; ks < 2; ks++) {
        const int cb = ks * 64 + ((lane >> 4) * 16);
        af[mi][ks] = *(const bf16x8*)(As + r * 128 + (cb ^ ((r & 7) << 4)));
      }
    }
    #pragma unroll
    for (int ni = 0; ni < NI; ni++) {
      const int r = wc * (NI * 16) + ni * 16 + (lane & 15);
      #pragma unroll
      for (int ks = 0; ks < 2; ks++) {
        const int cb = ks * 64 + ((lane >> 4) * 16);
        bfr[ni][ks] = *(const bf16x8*)(Bs + r * 128 + (cb ^ ((r & 7) << 4)));
      }
    }
    #pragma unroll
    for (int ks = 0; ks < 2; ks++)
      #pragma unroll
      for (int mi = 0; mi < 4; mi++)
        #pragma unroll
        for (int ni = 0; ni < NI; ni++)
          acc[mi][ni] = __builtin_amdgcn_mfma_f32_16x16x32_bf16(af[mi][ks], bfr[ni][ks], acc[mi][ni], 0, 0, 0);
    __syncthreads();
  }

  #pragma unroll
  for (int mi = 0; mi < 4; mi++) {
    #pragma unroll
    for (int ni = 0; ni < NI; ni++) {
      const int col = bn + wc * (NI * 16) + ni * 16 + (lane & 15);
      float bv = 0.f;
      if (EPI != EPI_NONE) bv = bias[col];
      #pragma unroll
      for (int r = 0; r < 4; r++) {
        const int row = bm + wr * 64 + mi * 16 + ((lane >> 4) << 2) + r;
        const float vacc = acc[mi][ni][r];
        const size_t idx = (size_t)row * N + col;
        if (EPI == EPI_NONE) {
          ((obf*)Cout)[idx] = __float2bfloat16(vacc);
        } else if (EPI == EPI_BIAS_RES_F32OUT) {
          const float x0 = ((const float*)resid)[idx];
          ((float*)Cout)[idx] = vacc + bv + x0;
        } else if (EPI == EPI_BIAS_GELU) {
          const float u = vacc + bv;
          const float e = exp2f(-2.30218709f * (u + 0.044715f * u * u * u));
          ((obf*)Cout)[idx] = __float2bfloat16(u / (1.f + e));
        } else {   // EPI_BIAS_RESF32_F32OUT
          const float x0 = ((const float*)resid)[idx];
          ((float*)Cout)[idx] = vacc + bv + x0;
        }
      }
    }
  }
}

// ---------------- Flash attention fwd ----------------
// ROUND-22: vtrans eliminated. V staged directly from the fused qkv buffer;
// the transpose happens in the existing reg->LDS ds_write (8 scalar b16
// scatter per thread; XOR swizzle spreads the 8 target rows across distinct
// 16B slots -> 32 banks at 2-way aliasing = free per m136). Otherwise the
// pinned r16 structure: KV=64, 8 waves/512 thr, Q-tile 128, no-max softmax,
// XCD swizzle, dbuf Ks/Vs, ONE barrier per tile, T14 reg prefetch.
__global__ void __launch_bounds__(512, 2) attn_kernel(
    const obf* __restrict__ qkv_, obf* __restrict__ ao)
{
  const __bf16* qkv = (const __bf16*)qkv_;
  const int bid = blockIdx.x;            // 0..511
  const int xcd = bid & 7, idx = bid >> 3;
  const int bh = xcd * 4 + (idx >> 4);   // 4 bh per XCD (K/V L2-resident)
  const int q0 = (idx & 15) * 128;
  const int b = bh >> 4, h = bh & 15;
  const int tid = threadIdx.x, lane = tid & 63, w = tid >> 6;   // w 0..7
  const int l15 = lane & 15, hi = lane >> 4;

  __shared__ __align__(16) char Ks[2][64 * 128];   // [kv=64][d=64]*2B, swizzled
  __shared__ __align__(16) char Vs[2][64 * 128];   // [d=64][kv=64]*2B, swizzled
  __shared__ __align__(16) char Ps[8 * 16 * 128];  // per-wave [16 q][64 kv]*2B, swz

  bf16x8 qf[2];
  {
    const int qrow = q0 + w * 16 + l15;
    #pragma unroll
    for (int ks = 0; ks < 2; ks++)
      qf[ks] = *(const bf16x8*)(qkv + ((size_t)(b * 2048 + qrow)) * 3072 + h * 64 + ks * 32 + hi * 8);
  }

  f32x4 o[4];
  #pragma unroll
  for (int j = 0; j < 4; j++) { o[j][0]=0.f; o[j][1]=0.f; o[j][2]=0.f; o[j][3]=0.f; }
  float lrow[4] = { 0.f, 0.f, 0.f, 0.f };

  const float kfac = 0.125f * 1.44269504089f;  // scale * log2(e)

  const int kr = tid >> 3, kc = (tid & 7) * 8;   // staging coords (1 chunk/thread)
  const int kcb = (tid & 7) * 16;
  const int kswz = kcb ^ ((kr & 7) << 4);

  // V transpose-write targets: thread's bf16x8 covers V[kt+kr][kc..kc+8];
  // element j goes to Vs[d=kc+j][kv=kr] at byte (kr*2) ^ ((d&7)<<4).
  bf16x8 pk, pv;
  pk = *(const bf16x8*)(qkv + ((size_t)(b * 2048 + kr)) * 3072 + 1024 + h * 64 + kc);
  pv = *(const bf16x8*)(qkv + ((size_t)(b * 2048 + kr)) * 3072 + 2048 + h * 64 + kc);
  *(bf16x8*)(Ks[0] + kr * 128 + kswz) = pk;
  #pragma unroll
  for (int j = 0; j < 8; j++) {
    const int d = kc + j;
    *(__bf16*)(Vs[0] + d * 128 + ((kr * 2) ^ ((d & 7) << 4))) = pv[j];
  }
  __syncthreads();

  for (int kt = 0; kt < 2048; kt += 64) {
    const int cur = (kt >> 6) & 1;
    if (kt + 64 < 2048) {
      pk = *(const bf16x8*)(qkv + ((size_t)(b * 2048 + kt + 64 + kr)) * 3072 + 1024 + h * 64 + kc);
      pv = *(const bf16x8*)(qkv + ((size_t)(b * 2048 + kt + 64 + kr)) * 3072 + 2048 + h * 64 + kc);
    }

    f32x4 s[4];
    #pragma unroll
    for (int j = 0; j < 4; j++) { s[j][0]=0.f; s[j][1]=0.f; s[j][2]=0.f; s[j][3]=0.f; }
    #pragma unroll
    for (int ni = 0; ni < 4; ni++) {
      const int r = ni * 16 + l15;
      const bf16x8 kf0 = *(const bf16x8*)(Ks[cur] + r * 128 + ((hi * 16) ^ ((r & 7) << 4)));
      const bf16x8 kf1 = *(const bf16x8*)(Ks[cur] + r * 128 + ((64 + hi * 16) ^ ((r & 7) << 4)));
      s[ni] = __builtin_amdgcn_mfma_f32_16x16x32_bf16(qf[0], kf0, s[ni], 0, 0, 0);
      s[ni] = __builtin_amdgcn_mfma_f32_16x16x32_bf16(qf[1], kf1, s[ni], 0, 0, 0);
    }

    #pragma unroll
    for (int r = 0; r < 4; r++) {
      const int qrl = (hi << 2) + r;
      char* psrow = Ps + w * 2048 + qrl * 128;
      float psum = 0.f;
      #pragma unroll
      for (int ni = 0; ni < 4; ni++) {
        const float p = exp2f(s[ni][r] * kfac);
        psum += p;
        *(__bf16*)(psrow + (((ni * 16 + l15) * 2) ^ ((qrl & 7) << 4))) = (__bf16)p;
      }
      lrow[r] += psum;
    }

    #pragma unroll
    for (int ks = 0; ks < 2; ks++) {
      const int rr = l15;
      const bf16x8 pa = *(const bf16x8*)(Ps + w * 2048 + rr * 128 + (((ks * 32 + hi * 8) * 2) ^ ((rr & 7) << 4)));
      #pragma unroll
      for (int df = 0; df < 4; df++) {
        const int dr = df * 16 + l15;
        const int cb = (ks * 32 + hi * 8) * 2;
        const bf16x8 vb = *(const bf16x8*)(Vs[cur] + dr * 128 + (cb ^ ((dr & 7) << 4)));
        o[df] = __builtin_amdgcn_mfma_f32_16x16x32_bf16(pa, vb, o[df], 0, 0, 0);
      }
    }

    if (kt + 64 < 2048) {
      *(bf16x8*)(Ks[cur ^ 1] + kr * 128 + kswz) = pk;
      #pragma unroll
      for (int j = 0; j < 8; j++) {
        const int d = kc + j;
        *(__bf16*)(Vs[cur ^ 1] + d * 128 + ((kr * 2) ^ ((d & 7) << 4))) = pv[j];
      }
    }
    __syncthreads();
  }

  #pragma unroll
  for (int r = 0; r < 4; r++) {
    lrow[r] += __shfl_xor(lrow[r], 1);
    lrow[r] += __shfl_xor(lrow[r], 2);
    lrow[r] += __shfl_xor(lrow[r], 4);
    lrow[r] += __shfl_xor(lrow[r], 8);
  }
  #pragma unroll
  for (int r = 0; r < 4; r++) {
    const float inv = 1.f / lrow[r];
    const int qrow = q0 + w * 16 + (hi << 2) + r;
    #pragma unroll
    for (int df = 0; df < 4; df++) {
      const int col = h * 64 + df * 16 + l15;
      ao[((size_t)(b * 2048 + qrow)) * 1024 + col] = __float2bfloat16(o[df][r] * inv);
    }
  }
}

// ---------------- launch ----------------
// ws layout (64 MB total, slots time-multiplexed):
//   [ 0,16M)  x2   f32 [4096][1024]
//   [16,24M)  h    bf16 [4096][1024]          -> later wb_w2 (8MB) after h dies
//   [24,48M)  qkv  bf16 [4096][3072]          -> later part of m1
//   [48,56M)  ao   bf16 [4096][1024]          -> later part of m1 (m1 spans 24..56M)
//   [56,64M)  SLOT: wb_qkv(6M)+wb_proj(2M) -> wb_w1(8M)
// 8 dispatches (vtrans eliminated; f2b(proj_w) merged into dispatch 0).
extern "C" void kernel_launch(void* const* d_in, const int* in_sizes, int n_in,
                              void* d_out, int out_size, void* d_ws, size_t ws_size,
                              hipStream_t stream) {
  const float* x      = (const float*)d_in[0];
  const float* ln1_g  = (const float*)d_in[1];
  const float* ln1_b  = (const float*)d_in[2];
  const float* qkv_w  = (const float*)d_in[3];
  const float* proj_w = (const float*)d_in[4];
  const float* proj_b = (const float*)d_in[5];
  const float* ln2_g  = (const float*)d_in[6];
  const float* ln2_b  = (const float*)d_in[7];
  const float* w1     = (const float*)d_in[8];
  const float* b1     = (const float*)d_in[9];
  const float* w2     = (const float*)d_in[10];
  const float* b2     = (const float*)d_in[11];
  float* out = (float*)d_out;                       // reference output dtype: float32

  char* ws = (char*)d_ws;
  float* x2   = (float*)ws;                        // 16 MB
  obf*   h    = (obf*)(ws + (16u << 20));          //  8 MB
  obf*   qkv  = (obf*)(ws + (24u << 20));          // 24 MB
  obf*   ao   = (obf*)(ws + (48u << 20));          //  8 MB
  obf*   m1   = (obf*)(ws + (24u << 20));          // 32 MB (overlays qkv+ao, both dead)
  __bf16* wb_qkv  = (__bf16*)(ws + (56u << 20));   //  6 MB
  __bf16* wb_proj = (__bf16*)(ws + (62u << 20));   //  2 MB
  __bf16* wb_w1   = (__bf16*)(ws + (56u << 20));   //  8 MB (overwrites qkv+proj wb)
  __bf16* wb_w2   = (__bf16*)(ws + (16u << 20));   //  8 MB (overlays h after it dies)

  const int M = 4096;

  // 0. merged: LN1 (x -> h) + f2b(qkv_w) + f2b(proj_w)
  ln_f2b2_kernel<<<M + 1536 + 512, 256, 0, stream>>>(
      x, ln1_g, ln1_b, h,
      qkv_w, wb_qkv, 3072 * 1024 / 8, 1536,
      proj_w, wb_proj, 1024 * 1024 / 8, M);
  // 1. qkv = h @ qkv_w^T
  gemm_bt<EPI_NONE, 4><<<dim3(3072 / 128, M / 128), 256, 0, stream>>>(
      h, (const obf*)wb_qkv, qkv, nullptr, nullptr, M, 3072, 1024);
  // 2. attention -> ao   (V transposed in-kernel; no vtrans)
  attn_kernel<<<512, 512, 0, stream>>>(qkv, ao);
  // 3. x2 = x + ao @ proj_w^T + proj_b   (f32 out; BN=64 -> 512 blocks)
  gemm_bt<EPI_BIAS_RES_F32OUT, 2><<<dim3(1024 / 64, M / 128), 256, 0, stream>>>(
      ao, (const obf*)wb_proj, x2, proj_b, x, M, 1024, 1024);
  // 4. merged: LN2 (x2 -> h) + f2b(w1)   (overwrites wb_qkv/wb_proj, now dead)
  ln_f2b2_kernel<<<M + 2048, 256, 0, stream>>>(
      x2, ln2_g, ln2_b, h,
      w1, wb_w1, 4096 * 1024 / 8, 2048,
      nullptr, nullptr, 0, M);
  // 5. m1 = gelu(h @ w1^T + b1)   (tanh-GELU epilogue)
  gemm_bt<EPI_BIAS_GELU, 4><<<dim3(4096 / 128, M / 128), 256, 0, stream>>>(
      h, (const obf*)wb_w1, m1, b1, nullptr, M, 4096, 1024);
  // 6. wb_w2 = bf16(w2)   (overwrites h, now dead)
  f2b_kernel<<<(4096 * 1024 / 8 + 255) / 256, 256, 0, stream>>>(w2, wb_w2, 4096 * 1024 / 8);
  // 7. out = x2 + m1 @ w2^T + b2   (f32 out -> d_out; BN=64 -> 512 blocks)
  gemm_bt<EPI_BIAS_RESF32_F32OUT, 2><<<dim3(1024 / 64, M / 128), 256, 0, stream>>>(
      m1, (const obf*)wb_w2, out, b2, x2, M, 1024, 4096);
}

// Round 23
// 242.852 us; speedup vs baseline: 1.0308x; 1.0308x over previous
//
#include <hip/hip_runtime.h>
#include <hip/hip_bf16.h>

typedef __hip_bfloat16 obf;
typedef __attribute__((ext_vector_type(8))) __bf16 bf16x8;
typedef __attribute__((ext_vector_type(4))) float f32x4;

#define DEVINL __device__ __forceinline__

DEVINL void gload_lds16(const void* g, void* l) {
  __builtin_amdgcn_global_load_lds((const __attribute__((address_space(1))) void*)g,
                                   (__attribute__((address_space(3))) void*)l,
                                   16, 0, 0);
}

// ---------------- f32 -> bf16 conversion (weights) ----------------
__global__ void __launch_bounds__(256) f2b_kernel(const float* __restrict__ in,
                                                  __bf16* __restrict__ out, int n8)
{
  const int i = blockIdx.x * 256 + threadIdx.x;
  if (i >= n8) return;
  const float4 a = ((const float4*)in)[i * 2];
  const float4 b = ((const float4*)in)[i * 2 + 1];
  bf16x8 o;
  o[0] = (__bf16)a.x; o[1] = (__bf16)a.y; o[2] = (__bf16)a.z; o[3] = (__bf16)a.w;
  o[4] = (__bf16)b.x; o[5] = (__bf16)b.y; o[6] = (__bf16)b.z; o[7] = (__bf16)b.w;
  ((bf16x8*)out)[i] = o;
}

// ---------------- merged LayerNorm + f2b (independent work, one dispatch) ----------------
// blocks [0, nln): LN row kernel (f32 in -> bf16 out, C=1024)
// blocks [nln, ...): f2b of win -> wout (n8 bf16x8 chunks)
__global__ void __launch_bounds__(256) ln_f2b_kernel(
    const float* __restrict__ xin, const float* __restrict__ g, const float* __restrict__ b,
    obf* __restrict__ lnout, const float* __restrict__ win, __bf16* __restrict__ wout,
    int nln, int n8)
{
  __shared__ float red[8];
  const int t = threadIdx.x;
  if ((int)blockIdx.x < nln) {
    const int row = blockIdx.x;
    const int lane = t & 63, w = t >> 6;
    float4 f = ((const float4*)xin)[(size_t)row * 256 + t];
    float v[4] = { f.x, f.y, f.z, f.w };
    float s1 = v[0] + v[1] + v[2] + v[3];
    float s2 = v[0]*v[0] + v[1]*v[1] + v[2]*v[2] + v[3]*v[3];
    #pragma unroll
    for (int off = 32; off >= 1; off >>= 1) {
      s1 += __shfl_xor(s1, off);
      s2 += __shfl_xor(s2, off);
    }
    if (lane == 0) { red[w] = s1; red[4 + w] = s2; }
    __syncthreads();
    s1 = red[0] + red[1] + red[2] + red[3];
    s2 = red[4] + red[5] + red[6] + red[7];
    const float mu = s1 * (1.f / 1024.f);
    const float var = s2 * (1.f / 1024.f) - mu * mu;
    const float rs = rsqrtf(var + 1e-5f);
    const float4 gv = ((const float4*)g)[t];
    const float4 bv = ((const float4*)b)[t];
    obf* op = lnout + (size_t)row * 1024 + t * 4;
    op[0] = __float2bfloat16((v[0] - mu) * rs * gv.x + bv.x);
    op[1] = __float2bfloat16((v[1] - mu) * rs * gv.y + bv.y);
    op[2] = __float2bfloat16((v[2] - mu) * rs * gv.z + bv.z);
    op[3] = __float2bfloat16((v[3] - mu) * rs * gv.w + bv.w);
  } else {
    const int i = (blockIdx.x - nln) * 256 + t;
    if (i >= n8) return;
    const float4 a = ((const float4*)win)[i * 2];
    const float4 b2 = ((const float4*)win)[i * 2 + 1];
    bf16x8 o;
    o[0] = (__bf16)a.x;  o[1] = (__bf16)a.y;  o[2] = (__bf16)a.z;  o[3] = (__bf16)a.w;
    o[4] = (__bf16)b2.x; o[5] = (__bf16)b2.y; o[6] = (__bf16)b2.z; o[7] = (__bf16)b2.w;
    ((bf16x8*)wout)[i] = o;
  }
}

// ---------------- GEMM 128-tile: C[M,N] = A[M,K] @ W[N,K]^T (+ epilogue) ----------------
// FINAL pinned form: single-buffer 2-barrier, 32KB LDS, ~3.4-4 blocks/CU.
// GELU epilogue: tanh form (validated r21, absmax unchanged).
enum { EPI_NONE = 0, EPI_BIAS_RES_F32OUT = 1, EPI_BIAS_GELU = 2, EPI_BIAS_RESF32_F32OUT = 3 };

template<int EPI, int NI>
__global__ void __launch_bounds__(256, 2) gemm_bt(
    const obf* __restrict__ A, const obf* __restrict__ Bw,
    void* __restrict__ Cout, const float* __restrict__ bias,
    const void* __restrict__ resid, int M, int N, int K)
{
  __shared__ __align__(16) char As[128 * 64 * 2];
  __shared__ __align__(16) char Bs[NI * 32 * 64 * 2];
  const int tid = threadIdx.x;
  const int lane = tid & 63;
  const int w = tid >> 6, wr = w >> 1, wc = w & 1;
  const int bm = blockIdx.y * 128, bn = blockIdx.x * (NI * 32);
  const size_t lda = (size_t)K * 2;

  f32x4 acc[4][NI];
  #pragma unroll
  for (int i = 0; i < 4; i++)
    #pragma unroll
    for (int j = 0; j < NI; j++) {
      acc[i][j][0] = 0.f; acc[i][j][1] = 0.f; acc[i][j][2] = 0.f; acc[i][j][3] = 0.f;
    }

  for (int k0 = 0; k0 < K; k0 += 64) {
    #pragma unroll
    for (int i = 0; i < 4; i++) {
      const int ci = tid + 256 * i;
      const int r = ci >> 3;
      const int gb = ((ci & 7) * 16) ^ ((r & 7) << 4);
      gload_lds16((const char*)A + (size_t)(bm + r) * lda + (size_t)k0 * 2 + gb, As + ci * 16);
    }
    #pragma unroll
    for (int i = 0; i < NI; i++) {
      const int ci = tid + 256 * i;
      const int r = ci >> 3;
      const int gb = ((ci & 7) * 16) ^ ((r & 7) << 4);
      gload_lds16((const char*)Bw + (size_t)(bn + r) * lda + (size_t)k0 * 2 + gb, Bs + ci * 16);
    }
    __syncthreads();

    bf16x8 af[4][2], bfr[NI][2];
    #pragma unroll
    for (int mi = 0; mi < 4; mi++) {
      const int r = wr * 64 + mi * 16 + (lane & 15);
      #pragma unroll
      for (int ks = 0; ks < 2; ks++) {
        const int cb = ks * 64 + ((lane >> 4) * 16);
        af[mi][ks] = *(const bf16x8*)(As + r * 128 + (cb ^ ((r & 7) << 4)));
      }
    }
    #pragma unroll
    for (int ni = 0; ni < NI; ni++) {
      const int r = wc * (NI * 16) + ni * 16 + (lane & 15);
      #pragma unroll
      for (int ks = 0; ks < 2; ks++) {
        const int cb = ks * 64 + ((lane >> 4) * 16);
        bfr[ni][ks] = *(const bf16x8*)(Bs + r * 128 + (cb ^ ((r & 7) << 4)));
      }
    }
    #pragma unroll
    for (int ks = 0; ks < 2; ks++)
      #pragma unroll
      for (int mi = 0; mi < 4; mi++)
        #pragma unroll
        for (int ni = 0; ni < NI; ni++)
          acc[mi][ni] = __builtin_amdgcn_mfma_f32_16x16x32_bf16(af[mi][ks], bfr[ni][ks], acc[mi][ni], 0, 0, 0);
    __syncthreads();
  }

  #pragma unroll
  for (int mi = 0; mi < 4; mi++) {
    #pragma unroll
    for (int ni = 0; ni < NI; ni++) {
      const int col = bn + wc * (NI * 16) + ni * 16 + (lane & 15);
      float bv = 0.f;
      if (EPI != EPI_NONE) bv = bias[col];
      #pragma unroll
      for (int r = 0; r < 4; r++) {
        const int row = bm + wr * 64 + mi * 16 + ((lane >> 4) << 2) + r;
        const float vacc = acc[mi][ni][r];
        const size_t idx = (size_t)row * N + col;
        if (EPI == EPI_NONE) {
          ((obf*)Cout)[idx] = __float2bfloat16(vacc);
        } else if (EPI == EPI_BIAS_RES_F32OUT) {
          const float x0 = ((const float*)resid)[idx];
          ((float*)Cout)[idx] = vacc + bv + x0;
        } else if (EPI == EPI_BIAS_GELU) {
          const float u = vacc + bv;
          const float e = exp2f(-2.30218709f * (u + 0.044715f * u * u * u));
          ((obf*)Cout)[idx] = __float2bfloat16(u / (1.f + e));
        } else {   // EPI_BIAS_RESF32_F32OUT
          const float x0 = ((const float*)resid)[idx];
          ((float*)Cout)[idx] = vacc + bv + x0;
        }
      }
    }
  }
}

// ---------------- V transpose: vt[b][h][d][n] = qkv[b][n][2C + h*64 + d] ----------------
// Restored (r22's in-kernel scatter was a 14.7M-cycle bank conflict: for each
// write j, d&7=j&7 is lane-invariant so the XOR term doesn't spread lanes).
__global__ void __launch_bounds__(256) vtrans_kernel(const obf* __restrict__ qkv, obf* __restrict__ vt)
{
  const int bh = blockIdx.y;             // 0..31  (b*16+h)
  const int b = bh >> 4, h = bh & 15;
  const int n0 = blockIdx.x * 64;        // 32 tiles over N=2048
  __shared__ __bf16 tile[64][72];        // +8 pad
  const int t = threadIdx.x;
  {
    const int n = t >> 2;
    const int c0 = (t & 3) * 16;
    const __bf16* src = (const __bf16*)qkv + ((size_t)(b * 2048 + n0 + n)) * 3072 + 2048 + h * 64 + c0;
    bf16x8 u0 = *(const bf16x8*)src;
    bf16x8 u1 = *(const bf16x8*)(src + 8);
    #pragma unroll
    for (int j = 0; j < 8; j++) { tile[n][c0 + j] = u0[j]; tile[n][c0 + 8 + j] = u1[j]; }
  }
  __syncthreads();
  {
    const int d = t >> 2;
    const int c0 = (t & 3) * 16;
    bf16x8 o0, o1;
    #pragma unroll
    for (int j = 0; j < 8; j++) { o0[j] = tile[c0 + j][d]; o1[j] = tile[c0 + 8 + j][d]; }
    __bf16* dst = (__bf16*)vt + ((size_t)bh * 64 + d) * 2048 + n0 + c0;
    *(bf16x8*)dst = o0;
    *(bf16x8*)(dst + 8) = o1;
  }
}

// ---------------- Flash attention fwd ----------------
// FINAL form (r16/r21): KV=64, 8 waves / 512 threads, Q-tile 128, no-max
// softmax, XCD swizzle, double-buffered Ks/Vs with ONE barrier per tile,
// T14 reg prefetch. LDS 48KB. V read from vt (coalesced vector ds_writes).
__global__ void __launch_bounds__(512, 2) attn_kernel(
    const obf* __restrict__ qkv_, const obf* __restrict__ vt_, obf* __restrict__ ao)
{
  const __bf16* qkv = (const __bf16*)qkv_;
  const __bf16* vt  = (const __bf16*)vt_;
  const int bid = blockIdx.x;            // 0..511
  const int xcd = bid & 7, idx = bid >> 3;
  const int bh = xcd * 4 + (idx >> 4);   // 4 bh per XCD (K/V L2-resident)
  const int q0 = (idx & 15) * 128;
  const int b = bh >> 4, h = bh & 15;
  const int tid = threadIdx.x, lane = tid & 63, w = tid >> 6;   // w 0..7
  const int l15 = lane & 15, hi = lane >> 4;

  __shared__ __align__(16) char Ks[2][64 * 128];   // [kv=64][d=64]*2B, swizzled
  __shared__ __align__(16) char Vs[2][64 * 128];   // [d=64][kv=64]*2B, swizzled
  __shared__ __align__(16) char Ps[8 * 16 * 128];  // per-wave [16 q][64 kv]*2B, swz

  bf16x8 qf[2];
  {
    const int qrow = q0 + w * 16 + l15;
    #pragma unroll
    for (int ks = 0; ks < 2; ks++)
      qf[ks] = *(const bf16x8*)(qkv + ((size_t)(b * 2048 + qrow)) * 3072 + h * 64 + ks * 32 + hi * 8);
  }

  f32x4 o[4];
  #pragma unroll
  for (int j = 0; j < 4; j++) { o[j][0]=0.f; o[j][1]=0.f; o[j][2]=0.f; o[j][3]=0.f; }
  float lrow[4] = { 0.f, 0.f, 0.f, 0.f };

  const float kfac = 0.125f * 1.44269504089f;  // scale * log2(e)

  const int kr = tid >> 3, kc = (tid & 7) * 8;   // staging coords (1 chunk/thread)
  const int kcb = (tid & 7) * 16;
  const int kswz = kcb ^ ((kr & 7) << 4);

  bf16x8 pk, pv;
  pk = *(const bf16x8*)(qkv + ((size_t)(b * 2048 + kr)) * 3072 + 1024 + h * 64 + kc);
  pv = *(const bf16x8*)(vt + ((size_t)bh * 64 + kr) * 2048 + kc);
  *(bf16x8*)(Ks[0] + kr * 128 + kswz) = pk;
  *(bf16x8*)(Vs[0] + kr * 128 + kswz) = pv;
  __syncthreads();

  for (int kt = 0; kt < 2048; kt += 64) {
    const int cur = (kt >> 6) & 1;
    if (kt + 64 < 2048) {
      pk = *(const bf16x8*)(qkv + ((size_t)(b * 2048 + kt + 64 + kr)) * 3072 + 1024 + h * 64 + kc);
      pv = *(const bf16x8*)(vt + ((size_t)bh * 64 + kr) * 2048 + kt + 64 + kc);
    }

    f32x4 s[4];
    #pragma unroll
    for (int j = 0; j < 4; j++) { s[j][0]=0.f; s[j][1]=0.f; s[j][2]=0.f; s[j][3]=0.f; }
    #pragma unroll
    for (int ni = 0; ni < 4; ni++) {
      const int r = ni * 16 + l15;
      const bf16x8 kf0 = *(const bf16x8*)(Ks[cur] + r * 128 + ((hi * 16) ^ ((r & 7) << 4)));
      const bf16x8 kf1 = *(const bf16x8*)(Ks[cur] + r * 128 + ((64 + hi * 16) ^ ((r & 7) << 4)));
      s[ni] = __builtin_amdgcn_mfma_f32_16x16x32_bf16(qf[0], kf0, s[ni], 0, 0, 0);
      s[ni] = __builtin_amdgcn_mfma_f32_16x16x32_bf16(qf[1], kf1, s[ni], 0, 0, 0);
    }

    #pragma unroll
    for (int r = 0; r < 4; r++) {
      const int qrl = (hi << 2) + r;
      char* psrow = Ps + w * 2048 + qrl * 128;
      float psum = 0.f;
      #pragma unroll
      for (int ni = 0; ni < 4; ni++) {
        const float p = exp2f(s[ni][r] * kfac);
        psum += p;
        *(__bf16*)(psrow + (((ni * 16 + l15) * 2) ^ ((qrl & 7) << 4))) = (__bf16)p;
      }
      lrow[r] += psum;
    }

    #pragma unroll
    for (int ks = 0; ks < 2; ks++) {
      const int rr = l15;
      const bf16x8 pa = *(const bf16x8*)(Ps + w * 2048 + rr * 128 + (((ks * 32 + hi * 8) * 2) ^ ((rr & 7) << 4)));
      #pragma unroll
      for (int df = 0; df < 4; df++) {
        const int dr = df * 16 + l15;
        const int cb = (ks * 32 + hi * 8) * 2;
        const bf16x8 vb = *(const bf16x8*)(Vs[cur] + dr * 128 + (cb ^ ((dr & 7) << 4)));
        o[df] = __builtin_amdgcn_mfma_f32_16x16x32_bf16(pa, vb, o[df], 0, 0, 0);
      }
    }

    if (kt + 64 < 2048) {
      *(bf16x8*)(Ks[cur ^ 1] + kr * 128 + kswz) = pk;
      *(bf16x8*)(Vs[cur ^ 1] + kr * 128 + kswz) = pv;
    }
    __syncthreads();
  }

  #pragma unroll
  for (int r = 0; r < 4; r++) {
    lrow[r] += __shfl_xor(lrow[r], 1);
    lrow[r] += __shfl_xor(lrow[r], 2);
    lrow[r] += __shfl_xor(lrow[r], 4);
    lrow[r] += __shfl_xor(lrow[r], 8);
  }
  #pragma unroll
  for (int r = 0; r < 4; r++) {
    const float inv = 1.f / lrow[r];
    const int qrow = q0 + w * 16 + (hi << 2) + r;
    #pragma unroll
    for (int df = 0; df < 4; df++) {
      const int col = h * 64 + df * 16 + l15;
      ao[((size_t)(b * 2048 + qrow)) * 1024 + col] = __float2bfloat16(o[df][r] * inv);
    }
  }
}

// ---------------- launch ----------------
// ws layout (64 MB total, slots time-multiplexed):
//   [ 0,16M)  x2   f32 [4096][1024]
//   [16,24M)  h    bf16 [4096][1024]          -> later wb_w2 (8MB) after h dies
//   [24,48M)  qkv  bf16 [4096][3072]          -> later part of m1
//   [48,56M)  ao   bf16 [4096][1024]          -> later part of m1 (m1 spans 24..56M)
//   [56,64M)  SLOT: wb_qkv(6M) -> vt(8M) -> wb_proj(2M) -> wb_w1(8M)
// 10 dispatches (r21 configuration, session best: 243.1 us).
extern "C" void kernel_launch(void* const* d_in, const int* in_sizes, int n_in,
                              void* d_out, int out_size, void* d_ws, size_t ws_size,
                              hipStream_t stream) {
  const float* x      = (const float*)d_in[0];
  const float* ln1_g  = (const float*)d_in[1];
  const float* ln1_b  = (const float*)d_in[2];
  const float* qkv_w  = (const float*)d_in[3];
  const float* proj_w = (const float*)d_in[4];
  const float* proj_b = (const float*)d_in[5];
  const float* ln2_g  = (const float*)d_in[6];
  const float* ln2_b  = (const float*)d_in[7];
  const float* w1     = (const float*)d_in[8];
  const float* b1     = (const float*)d_in[9];
  const float* w2     = (const float*)d_in[10];
  const float* b2     = (const float*)d_in[11];
  float* out = (float*)d_out;                       // reference output dtype: float32

  char* ws = (char*)d_ws;
  float* x2   = (float*)ws;                        // 16 MB
  obf*   h    = (obf*)(ws + (16u << 20));          //  8 MB
  obf*   qkv  = (obf*)(ws + (24u << 20));          // 24 MB
  obf*   ao   = (obf*)(ws + (48u << 20));          //  8 MB
  obf*   m1   = (obf*)(ws + (24u << 20));          // 32 MB (overlays qkv+ao, both dead)
  __bf16* slot = (__bf16*)(ws + (56u << 20));      //  8 MB multi-use
  __bf16* wb_w2 = (__bf16*)(ws + (16u << 20));     //  8 MB (overlays h after it dies)

  const int M = 4096;

  // 0+1. merged: LN1 (x -> h) + wb_qkv = bf16(qkv_w)
  ln_f2b_kernel<<<M + 1536, 256, 0, stream>>>(x, ln1_g, ln1_b, h,
                                              qkv_w, slot, M, 3072 * 1024 / 8);
  // 2. qkv = h @ qkv_w^T
  gemm_bt<EPI_NONE, 4><<<dim3(3072 / 128, M / 128), 256, 0, stream>>>(
      h, (const obf*)slot, qkv, nullptr, nullptr, M, 3072, 1024);
  // 3. vt = transpose(V)   (overwrites wb_qkv, now dead)
  vtrans_kernel<<<dim3(32, 32), 256, 0, stream>>>(qkv, (obf*)slot);
  // 4. attention -> ao   (512 blocks x 512 threads, KV=64 dbuf 1-barrier)
  attn_kernel<<<512, 512, 0, stream>>>(qkv, (const obf*)slot, ao);
  // 5. wb_proj = bf16(proj_w)   (overwrites vt, now dead)
  f2b_kernel<<<(1024 * 1024 / 8 + 255) / 256, 256, 0, stream>>>(proj_w, slot, 1024 * 1024 / 8);
  // 6. x2 = x + ao @ proj_w^T + proj_b   (f32 out; BN=64 -> 512 blocks)
  gemm_bt<EPI_BIAS_RES_F32OUT, 2><<<dim3(1024 / 64, M / 128), 256, 0, stream>>>(
      ao, (const obf*)slot, x2, proj_b, x, M, 1024, 1024);
  // 7+8. merged: LN2 (x2 -> h) + wb_w1 = bf16(w1)   (overwrites wb_proj, now dead)
  ln_f2b_kernel<<<M + 2048, 256, 0, stream>>>(x2, ln2_g, ln2_b, h,
                                              w1, slot, M, 4096 * 1024 / 8);
  // 9. m1 = gelu(h @ w1^T + b1)   (tanh-GELU epilogue)
  gemm_bt<EPI_BIAS_GELU, 4><<<dim3(4096 / 128, M / 128), 256, 0, stream>>>(
      h, (const obf*)slot, m1, b1, nullptr, M, 4096, 1024);
  // 10. wb_w2 = bf16(w2)   (overwrites h, now dead)
  f2b_kernel<<<(4096 * 1024 / 8 + 255) / 256, 256, 0, stream>>>(w2, wb_w2, 4096 * 1024 / 8);
  // 11. out = x2 + m1 @ w2^T + b2   (f32 out -> d_out; BN=64 -> 512 blocks)
  gemm_bt<EPI_BIAS_RESF32_F32OUT, 2><<<dim3(1024 / 64, M / 128), 256, 0, stream>>>(
      m1, (const obf*)wb_w2, out, b2, x2, M, 1024, 4096);
}

// Round 24
// 233.787 us; speedup vs baseline: 1.0708x; 1.0388x over previous
//
#include <hip/hip_runtime.h>
#include <hip/hip_bf16.h>

typedef __hip_bfloat16 obf;
typedef __attribute__((ext_vector_type(8))) __bf16 bf16x8;
typedef __attribute__((ext_vector_type(4))) float f32x4;

#define DEVINL __device__ __forceinline__

DEVINL void gload_lds16(const void* g, void* l) {
  __builtin_amdgcn_global_load_lds((const __attribute__((address_space(1))) void*)g,
                                   (__attribute__((address_space(3))) void*)l,
                                   16, 0, 0);
}

DEVINL float bf2f(unsigned short h) {
  union { unsigned int u; float f; } c; c.u = ((unsigned)h) << 16; return c.f;
}

// ------- merged LayerNorm + two f2b segments (independent work, one dispatch) -------
// blocks [0, nln): LN rows (input f32 or bf16 per template);
// [nln, nln+nb1): f2b win1; [nln+nb1, ...): f2b win2 (skip if n8_2==0).
template<bool INBF16>
__global__ void __launch_bounds__(256) ln_f2b2_kernel(
    const void* __restrict__ xin, const float* __restrict__ g, const float* __restrict__ b,
    obf* __restrict__ lnout,
    const float* __restrict__ win1, __bf16* __restrict__ wout1, int n8_1, int nb1,
    const float* __restrict__ win2, __bf16* __restrict__ wout2, int n8_2,
    int nln)
{
  __shared__ float red[8];
  const int t = threadIdx.x;
  const int bx = blockIdx.x;
  if (bx < nln) {
    const int row = bx;
    const int lane = t & 63, w = t >> 6;
    float v[4];
    if (INBF16) {
      ushort4 u = ((const ushort4*)xin)[(size_t)row * 256 + t];
      v[0] = bf2f(u.x); v[1] = bf2f(u.y); v[2] = bf2f(u.z); v[3] = bf2f(u.w);
    } else {
      float4 f = ((const float4*)xin)[(size_t)row * 256 + t];
      v[0] = f.x; v[1] = f.y; v[2] = f.z; v[3] = f.w;
    }
    float s1 = v[0] + v[1] + v[2] + v[3];
    float s2 = v[0]*v[0] + v[1]*v[1] + v[2]*v[2] + v[3]*v[3];
    #pragma unroll
    for (int off = 32; off >= 1; off >>= 1) {
      s1 += __shfl_xor(s1, off);
      s2 += __shfl_xor(s2, off);
    }
    if (lane == 0) { red[w] = s1; red[4 + w] = s2; }
    __syncthreads();
    s1 = red[0] + red[1] + red[2] + red[3];
    s2 = red[4] + red[5] + red[6] + red[7];
    const float mu = s1 * (1.f / 1024.f);
    const float var = s2 * (1.f / 1024.f) - mu * mu;
    const float rs = rsqrtf(var + 1e-5f);
    const float4 gv = ((const float4*)g)[t];
    const float4 bv = ((const float4*)b)[t];
    obf* op = lnout + (size_t)row * 1024 + t * 4;
    op[0] = __float2bfloat16((v[0] - mu) * rs * gv.x + bv.x);
    op[1] = __float2bfloat16((v[1] - mu) * rs * gv.y + bv.y);
    op[2] = __float2bfloat16((v[2] - mu) * rs * gv.z + bv.z);
    op[3] = __float2bfloat16((v[3] - mu) * rs * gv.w + bv.w);
  } else if (bx < nln + nb1) {
    const int i = (bx - nln) * 256 + t;
    if (i >= n8_1) return;
    const float4 a = ((const float4*)win1)[i * 2];
    const float4 b2 = ((const float4*)win1)[i * 2 + 1];
    bf16x8 o;
    o[0] = (__bf16)a.x;  o[1] = (__bf16)a.y;  o[2] = (__bf16)a.z;  o[3] = (__bf16)a.w;
    o[4] = (__bf16)b2.x; o[5] = (__bf16)b2.y; o[6] = (__bf16)b2.z; o[7] = (__bf16)b2.w;
    ((bf16x8*)wout1)[i] = o;
  } else {
    const int i = (bx - nln - nb1) * 256 + t;
    if (i >= n8_2) return;
    const float4 a = ((const float4*)win2)[i * 2];
    const float4 b2 = ((const float4*)win2)[i * 2 + 1];
    bf16x8 o;
    o[0] = (__bf16)a.x;  o[1] = (__bf16)a.y;  o[2] = (__bf16)a.z;  o[3] = (__bf16)a.w;
    o[4] = (__bf16)b2.x; o[5] = (__bf16)b2.y; o[6] = (__bf16)b2.z; o[7] = (__bf16)b2.w;
    ((bf16x8*)wout2)[i] = o;
  }
}

// ---------------- GEMM 128-tile: C[M,N] = A[M,K] @ W[N,K]^T (+ epilogue) ----------------
// Pinned form: single-buffer 2-barrier, 32KB LDS, ~3.4-4 blocks/CU.
// ROUND-24 epilogue changes: proj writes bf16 x2 (resid = f32 x input);
// mlp2 reads bf16 x2 residual, writes f32 d_out. tanh-GELU (validated r21).
enum { EPI_NONE = 0, EPI_BIAS_RES_BF16OUT = 1, EPI_BIAS_GELU = 2, EPI_BIAS_RESBF16_F32OUT = 3 };

template<int EPI, int NI>
__global__ void __launch_bounds__(256, 2) gemm_bt(
    const obf* __restrict__ A, const obf* __restrict__ Bw,
    void* __restrict__ Cout, const float* __restrict__ bias,
    const void* __restrict__ resid, int M, int N, int K)
{
  __shared__ __align__(16) char As[128 * 64 * 2];
  __shared__ __align__(16) char Bs[NI * 32 * 64 * 2];
  const int tid = threadIdx.x;
  const int lane = tid & 63;
  const int w = tid >> 6, wr = w >> 1, wc = w & 1;
  const int bm = blockIdx.y * 128, bn = blockIdx.x * (NI * 32);
  const size_t lda = (size_t)K * 2;

  f32x4 acc[4][NI];
  #pragma unroll
  for (int i = 0; i < 4; i++)
    #pragma unroll
    for (int j = 0; j < NI; j++) {
      acc[i][j][0] = 0.f; acc[i][j][1] = 0.f; acc[i][j][2] = 0.f; acc[i][j][3] = 0.f;
    }

  for (int k0 = 0; k0 < K; k0 += 64) {
    #pragma unroll
    for (int i = 0; i < 4; i++) {
      const int ci = tid + 256 * i;
      const int r = ci >> 3;
      const int gb = ((ci & 7) * 16) ^ ((r & 7) << 4);
      gload_lds16((const char*)A + (size_t)(bm + r) * lda + (size_t)k0 * 2 + gb, As + ci * 16);
    }
    #pragma unroll
    for (int i = 0; i < NI; i++) {
      const int ci = tid + 256 * i;
      const int r = ci >> 3;
      const int gb = ((ci & 7) * 16) ^ ((r & 7) << 4);
      gload_lds16((const char*)Bw + (size_t)(bn + r) * lda + (size_t)k0 * 2 + gb, Bs + ci * 16);
    }
    __syncthreads();

    bf16x8 af[4][2], bfr[NI][2];
    #pragma unroll
    for (int mi = 0; mi < 4; mi++) {
      const int r = wr * 64 + mi * 16 + (lane & 15);
      #pragma unroll
      for (int ks = 0; ks < 2; ks++) {
        const int cb = ks * 64 + ((lane >> 4) * 16);
        af[mi][ks] = *(const bf16x8*)(As + r * 128 + (cb ^ ((r & 7) << 4)));
      }
    }
    #pragma unroll
    for (int ni = 0; ni < NI; ni++) {
      const int r = wc * (NI * 16) + ni * 16 + (lane & 15);
      #pragma unroll
      for (int ks = 0; ks < 2; ks++) {
        const int cb = ks * 64 + ((lane >> 4) * 16);
        bfr[ni][ks] = *(const bf16x8*)(Bs + r * 128 + (cb ^ ((r & 7) << 4)));
      }
    }
    #pragma unroll
    for (int ks = 0; ks < 2; ks++)
      #pragma unroll
      for (int mi = 0; mi < 4; mi++)
        #pragma unroll
        for (int ni = 0; ni < NI; ni++)
          acc[mi][ni] = __builtin_amdgcn_mfma_f32_16x16x32_bf16(af[mi][ks], bfr[ni][ks], acc[mi][ni], 0, 0, 0);
    __syncthreads();
  }

  #pragma unroll
  for (int mi = 0; mi < 4; mi++) {
    #pragma unroll
    for (int ni = 0; ni < NI; ni++) {
      const int col = bn + wc * (NI * 16) + ni * 16 + (lane & 15);
      float bv = 0.f;
      if (EPI != EPI_NONE) bv = bias[col];
      #pragma unroll
      for (int r = 0; r < 4; r++) {
        const int row = bm + wr * 64 + mi * 16 + ((lane >> 4) << 2) + r;
        const float vacc = acc[mi][ni][r];
        const size_t idx = (size_t)row * N + col;
        if (EPI == EPI_NONE) {
          ((obf*)Cout)[idx] = __float2bfloat16(vacc);
        } else if (EPI == EPI_BIAS_RES_BF16OUT) {
          const float x0 = ((const float*)resid)[idx];           // f32 x input
          ((obf*)Cout)[idx] = __float2bfloat16(vacc + bv + x0);  // bf16 x2
        } else if (EPI == EPI_BIAS_GELU) {
          const float u = vacc + bv;
          const float e = exp2f(-2.30218709f * (u + 0.044715f * u * u * u));
          ((obf*)Cout)[idx] = __float2bfloat16(u / (1.f + e));
        } else {   // EPI_BIAS_RESBF16_F32OUT: bf16 x2 residual, f32 d_out
          const float x0 = __bfloat162float(((const obf*)resid)[idx]);
          ((float*)Cout)[idx] = vacc + bv + x0;
        }
      }
    }
  }
}

// ---------------- V transpose: vt[b][h][d][n] = qkv[b][n][2C + h*64 + d] ----------------
__global__ void __launch_bounds__(256) vtrans_kernel(const obf* __restrict__ qkv, obf* __restrict__ vt)
{
  const int bh = blockIdx.y;             // 0..31  (b*16+h)
  const int b = bh >> 4, h = bh & 15;
  const int n0 = blockIdx.x * 64;        // 32 tiles over N=2048
  __shared__ __bf16 tile[64][72];        // +8 pad
  const int t = threadIdx.x;
  {
    const int n = t >> 2;
    const int c0 = (t & 3) * 16;
    const __bf16* src = (const __bf16*)qkv + ((size_t)(b * 2048 + n0 + n)) * 3072 + 2048 + h * 64 + c0;
    bf16x8 u0 = *(const bf16x8*)src;
    bf16x8 u1 = *(const bf16x8*)(src + 8);
    #pragma unroll
    for (int j = 0; j < 8; j++) { tile[n][c0 + j] = u0[j]; tile[n][c0 + 8 + j] = u1[j]; }
  }
  __syncthreads();
  {
    const int d = t >> 2;
    const int c0 = (t & 3) * 16;
    bf16x8 o0, o1;
    #pragma unroll
    for (int j = 0; j < 8; j++) { o0[j] = tile[c0 + j][d]; o1[j] = tile[c0 + 8 + j][d]; }
    __bf16* dst = (__bf16*)vt + ((size_t)bh * 64 + d) * 2048 + n0 + c0;
    *(bf16x8*)dst = o0;
    *(bf16x8*)(dst + 8) = o1;
  }
}

// ---------------- Flash attention fwd ----------------
// Pinned form (r16/r21): KV=64, 8 waves / 512 threads, Q-tile 128, no-max
// softmax, XCD swizzle, double-buffered Ks/Vs with ONE barrier per tile,
// T14 reg prefetch. LDS 48KB. V read from vt.
__global__ void __launch_bounds__(512, 2) attn_kernel(
    const obf* __restrict__ qkv_, const obf* __restrict__ vt_, obf* __restrict__ ao)
{
  const __bf16* qkv = (const __bf16*)qkv_;
  const __bf16* vt  = (const __bf16*)vt_;
  const int bid = blockIdx.x;            // 0..511
  const int xcd = bid & 7, idx = bid >> 3;
  const int bh = xcd * 4 + (idx >> 4);   // 4 bh per XCD (K/V L2-resident)
  const int q0 = (idx & 15) * 128;
  const int b = bh >> 4, h = bh & 15;
  const int tid = threadIdx.x, lane = tid & 63, w = tid >> 6;   // w 0..7
  const int l15 = lane & 15, hi = lane >> 4;

  __shared__ __align__(16) char Ks[2][64 * 128];   // [kv=64][d=64]*2B, swizzled
  __shared__ __align__(16) char Vs[2][64 * 128];   // [d=64][kv=64]*2B, swizzled
  __shared__ __align__(16) char Ps[8 * 16 * 128];  // per-wave [16 q][64 kv]*2B, swz

  bf16x8 qf[2];
  {
    const int qrow = q0 + w * 16 + l15;
    #pragma unroll
    for (int ks = 0; ks < 2; ks++)
      qf[ks] = *(const bf16x8*)(qkv + ((size_t)(b * 2048 + qrow)) * 3072 + h * 64 + ks * 32 + hi * 8);
  }

  f32x4 o[4];
  #pragma unroll
  for (int j = 0; j < 4; j++) { o[j][0]=0.f; o[j][1]=0.f; o[j][2]=0.f; o[j][3]=0.f; }
  float lrow[4] = { 0.f, 0.f, 0.f, 0.f };

  const float kfac = 0.125f * 1.44269504089f;  // scale * log2(e)

  const int kr = tid >> 3, kc = (tid & 7) * 8;   // staging coords (1 chunk/thread)
  const int kcb = (tid & 7) * 16;
  const int kswz = kcb ^ ((kr & 7) << 4);

  bf16x8 pk, pv;
  pk = *(const bf16x8*)(qkv + ((size_t)(b * 2048 + kr)) * 3072 + 1024 + h * 64 + kc);
  pv = *(const bf16x8*)(vt + ((size_t)bh * 64 + kr) * 2048 + kc);
  *(bf16x8*)(Ks[0] + kr * 128 + kswz) = pk;
  *(bf16x8*)(Vs[0] + kr * 128 + kswz) = pv;
  __syncthreads();

  for (int kt = 0; kt < 2048; kt += 64) {
    const int cur = (kt >> 6) & 1;
    if (kt + 64 < 2048) {
      pk = *(const bf16x8*)(qkv + ((size_t)(b * 2048 + kt + 64 + kr)) * 3072 + 1024 + h * 64 + kc);
      pv = *(const bf16x8*)(vt + ((size_t)bh * 64 + kr) * 2048 + kt + 64 + kc);
    }

    f32x4 s[4];
    #pragma unroll
    for (int j = 0; j < 4; j++) { s[j][0]=0.f; s[j][1]=0.f; s[j][2]=0.f; s[j][3]=0.f; }
    #pragma unroll
    for (int ni = 0; ni < 4; ni++) {
      const int r = ni * 16 + l15;
      const bf16x8 kf0 = *(const bf16x8*)(Ks[cur] + r * 128 + ((hi * 16) ^ ((r & 7) << 4)));
      const bf16x8 kf1 = *(const bf16x8*)(Ks[cur] + r * 128 + ((64 + hi * 16) ^ ((r & 7) << 4)));
      s[ni] = __builtin_amdgcn_mfma_f32_16x16x32_bf16(qf[0], kf0, s[ni], 0, 0, 0);
      s[ni] = __builtin_amdgcn_mfma_f32_16x16x32_bf16(qf[1], kf1, s[ni], 0, 0, 0);
    }

    #pragma unroll
    for (int r = 0; r < 4; r++) {
      const int qrl = (hi << 2) + r;
      char* psrow = Ps + w * 2048 + qrl * 128;
      float psum = 0.f;
      #pragma unroll
      for (int ni = 0; ni < 4; ni++) {
        const float p = exp2f(s[ni][r] * kfac);
        psum += p;
        *(__bf16*)(psrow + (((ni * 16 + l15) * 2) ^ ((qrl & 7) << 4))) = (__bf16)p;
      }
      lrow[r] += psum;
    }

    #pragma unroll
    for (int ks = 0; ks < 2; ks++) {
      const int rr = l15;
      const bf16x8 pa = *(const bf16x8*)(Ps + w * 2048 + rr * 128 + (((ks * 32 + hi * 8) * 2) ^ ((rr & 7) << 4)));
      #pragma unroll
      for (int df = 0; df < 4; df++) {
        const int dr = df * 16 + l15;
        const int cb = (ks * 32 + hi * 8) * 2;
        const bf16x8 vb = *(const bf16x8*)(Vs[cur] + dr * 128 + (cb ^ ((dr & 7) << 4)));
        o[df] = __builtin_amdgcn_mfma_f32_16x16x32_bf16(pa, vb, o[df], 0, 0, 0);
      }
    }

    if (kt + 64 < 2048) {
      *(bf16x8*)(Ks[cur ^ 1] + kr * 128 + kswz) = pk;
      *(bf16x8*)(Vs[cur ^ 1] + kr * 128 + kswz) = pv;
    }
    __syncthreads();
  }

  #pragma unroll
  for (int r = 0; r < 4; r++) {
    lrow[r] += __shfl_xor(lrow[r], 1);
    lrow[r] += __shfl_xor(lrow[r], 2);
    lrow[r] += __shfl_xor(lrow[r], 4);
    lrow[r] += __shfl_xor(lrow[r], 8);
  }
  #pragma unroll
  for (int r = 0; r < 4; r++) {
    const float inv = 1.f / lrow[r];
    const int qrow = q0 + w * 16 + (hi << 2) + r;
    #pragma unroll
    for (int df = 0; df < 4; df++) {
      const int col = h * 64 + df * 16 + l15;
      ao[((size_t)(b * 2048 + qrow)) * 1024 + col] = __float2bfloat16(o[df][r] * inv);
    }
  }
}

// ---------------- launch ----------------
// ROUND-24 ws layout (64 MB, slots time-multiplexed):
//   [ 0, 8M)  x2   bf16 [4096][1024]   (written d4, read d5 + d7)
//   [ 8,16M)  vt (d2 write, d3 read)  ->  wb_w2 (d5 write, d7 read)
//   [16,24M)  h    bf16 [4096][1024]   (d0 write, d1 read; d5 write, d6 read)
//   [24,48M)  qkv  (d1 write, d2/d3 read)  -> part of m1
//   [48,56M)  ao   (d3 write, d4 read)     -> part of m1 (m1 = [24,56M), d6->d7)
//   [56,62M)  wb_qkv (d0 write, d1 read) \ -> wb_w1 [56,64M) (d5 write, d6 read)
//   [62,64M)  wb_proj (d0 write, d4 read)/
// 8 dispatches.
extern "C" void kernel_launch(void* const* d_in, const int* in_sizes, int n_in,
                              void* d_out, int out_size, void* d_ws, size_t ws_size,
                              hipStream_t stream) {
  const float* x      = (const float*)d_in[0];
  const float* ln1_g  = (const float*)d_in[1];
  const float* ln1_b  = (const float*)d_in[2];
  const float* qkv_w  = (const float*)d_in[3];
  const float* proj_w = (const float*)d_in[4];
  const float* proj_b = (const float*)d_in[5];
  const float* ln2_g  = (const float*)d_in[6];
  const float* ln2_b  = (const float*)d_in[7];
  const float* w1     = (const float*)d_in[8];
  const float* b1     = (const float*)d_in[9];
  const float* w2     = (const float*)d_in[10];
  const float* b2     = (const float*)d_in[11];
  float* out = (float*)d_out;                       // reference output dtype: float32

  char* ws = (char*)d_ws;
  obf*   x2      = (obf*)ws;                       //  8 MB bf16
  obf*   vt      = (obf*)(ws + ( 8u << 20));       //  8 MB (later wb_w2)
  __bf16* wb_w2  = (__bf16*)(ws + ( 8u << 20));
  obf*   h       = (obf*)(ws + (16u << 20));       //  8 MB
  obf*   qkv     = (obf*)(ws + (24u << 20));       // 24 MB
  obf*   ao      = (obf*)(ws + (48u << 20));       //  8 MB
  obf*   m1      = (obf*)(ws + (24u << 20));       // 32 MB (overlays qkv+ao)
  __bf16* wb_qkv  = (__bf16*)(ws + (56u << 20));   //  6 MB
  __bf16* wb_proj = (__bf16*)(ws + (62u << 20));   //  2 MB
  __bf16* wb_w1   = (__bf16*)(ws + (56u << 20));   //  8 MB (overwrites qkv/proj wb)

  const int M = 4096;

  // 0. merged: LN1 (x -> h) + f2b(qkv_w) + f2b(proj_w)
  ln_f2b2_kernel<false><<<M + 1536 + 512, 256, 0, stream>>>(
      x, ln1_g, ln1_b, h,
      qkv_w, wb_qkv, 3072 * 1024 / 8, 1536,
      proj_w, wb_proj, 1024 * 1024 / 8, M);
  // 1. qkv = h @ qkv_w^T
  gemm_bt<EPI_NONE, 4><<<dim3(3072 / 128, M / 128), 256, 0, stream>>>(
      h, (const obf*)wb_qkv, qkv, nullptr, nullptr, M, 3072, 1024);
  // 2. vt = transpose(V)
  vtrans_kernel<<<dim3(32, 32), 256, 0, stream>>>(qkv, vt);
  // 3. attention -> ao
  attn_kernel<<<512, 512, 0, stream>>>(qkv, vt, ao);
  // 4. x2 = bf16(x + ao @ proj_w^T + proj_b)
  gemm_bt<EPI_BIAS_RES_BF16OUT, 2><<<dim3(1024 / 64, M / 128), 256, 0, stream>>>(
      ao, (const obf*)wb_proj, x2, proj_b, x, M, 1024, 1024);
  // 5. merged: LN2 (bf16 x2 -> h) + f2b(w1) + f2b(w2)   (vt dead; wb_qkv/proj dead)
  ln_f2b2_kernel<true><<<M + 2048 + 2048, 256, 0, stream>>>(
      x2, ln2_g, ln2_b, h,
      w1, wb_w1, 4096 * 1024 / 8, 2048,
      w2, wb_w2, 4096 * 1024 / 8, M);
  // 6. m1 = gelu(h @ w1^T + b1)   (tanh-GELU)
  gemm_bt<EPI_BIAS_GELU, 4><<<dim3(4096 / 128, M / 128), 256, 0, stream>>>(
      h, (const obf*)wb_w1, m1, b1, nullptr, M, 4096, 1024);
  // 7. out = f32(x2 + m1 @ w2^T + b2) -> d_out
  gemm_bt<EPI_BIAS_RESBF16_F32OUT, 2><<<dim3(1024 / 64, M / 128), 256, 0, stream>>>(
      m1, (const obf*)wb_w2, out, b2, x2, M, 1024, 4096);
}

// Round 25
// 230.090 us; speedup vs baseline: 1.0880x; 1.0161x over previous
//
#include <hip/hip_runtime.h>
#include <hip/hip_bf16.h>

typedef __hip_bfloat16 obf;
typedef __attribute__((ext_vector_type(8))) __bf16 bf16x8;
typedef __attribute__((ext_vector_type(4))) float f32x4;

#define DEVINL __device__ __forceinline__

DEVINL void gload_lds16(const void* g, void* l) {
  __builtin_amdgcn_global_load_lds((const __attribute__((address_space(1))) void*)g,
                                   (__attribute__((address_space(3))) void*)l,
                                   16, 0, 0);
}

DEVINL float bf2f(unsigned short h) {
  union { unsigned int u; float f; } c; c.u = ((unsigned)h) << 16; return c.f;
}

// ------- merged LayerNorm + two f2b segments (independent work, one dispatch) -------
template<bool INBF16>
__global__ void __launch_bounds__(256) ln_f2b2_kernel(
    const void* __restrict__ xin, const float* __restrict__ g, const float* __restrict__ b,
    obf* __restrict__ lnout,
    const float* __restrict__ win1, __bf16* __restrict__ wout1, int n8_1, int nb1,
    const float* __restrict__ win2, __bf16* __restrict__ wout2, int n8_2,
    int nln)
{
  __shared__ float red[8];
  const int t = threadIdx.x;
  const int bx = blockIdx.x;
  if (bx < nln) {
    const int row = bx;
    const int lane = t & 63, w = t >> 6;
    float v[4];
    if (INBF16) {
      ushort4 u = ((const ushort4*)xin)[(size_t)row * 256 + t];
      v[0] = bf2f(u.x); v[1] = bf2f(u.y); v[2] = bf2f(u.z); v[3] = bf2f(u.w);
    } else {
      float4 f = ((const float4*)xin)[(size_t)row * 256 + t];
      v[0] = f.x; v[1] = f.y; v[2] = f.z; v[3] = f.w;
    }
    float s1 = v[0] + v[1] + v[2] + v[3];
    float s2 = v[0]*v[0] + v[1]*v[1] + v[2]*v[2] + v[3]*v[3];
    #pragma unroll
    for (int off = 32; off >= 1; off >>= 1) {
      s1 += __shfl_xor(s1, off);
      s2 += __shfl_xor(s2, off);
    }
    if (lane == 0) { red[w] = s1; red[4 + w] = s2; }
    __syncthreads();
    s1 = red[0] + red[1] + red[2] + red[3];
    s2 = red[4] + red[5] + red[6] + red[7];
    const float mu = s1 * (1.f / 1024.f);
    const float var = s2 * (1.f / 1024.f) - mu * mu;
    const float rs = rsqrtf(var + 1e-5f);
    const float4 gv = ((const float4*)g)[t];
    const float4 bv = ((const float4*)b)[t];
    obf* op = lnout + (size_t)row * 1024 + t * 4;
    op[0] = __float2bfloat16((v[0] - mu) * rs * gv.x + bv.x);
    op[1] = __float2bfloat16((v[1] - mu) * rs * gv.y + bv.y);
    op[2] = __float2bfloat16((v[2] - mu) * rs * gv.z + bv.z);
    op[3] = __float2bfloat16((v[3] - mu) * rs * gv.w + bv.w);
  } else if (bx < nln + nb1) {
    const int i = (bx - nln) * 256 + t;
    if (i >= n8_1) return;
    const float4 a = ((const float4*)win1)[i * 2];
    const float4 b2 = ((const float4*)win1)[i * 2 + 1];
    bf16x8 o;
    o[0] = (__bf16)a.x;  o[1] = (__bf16)a.y;  o[2] = (__bf16)a.z;  o[3] = (__bf16)a.w;
    o[4] = (__bf16)b2.x; o[5] = (__bf16)b2.y; o[6] = (__bf16)b2.z; o[7] = (__bf16)b2.w;
    ((bf16x8*)wout1)[i] = o;
  } else {
    const int i = (bx - nln - nb1) * 256 + t;
    if (i >= n8_2) return;
    const float4 a = ((const float4*)win2)[i * 2];
    const float4 b2 = ((const float4*)win2)[i * 2 + 1];
    bf16x8 o;
    o[0] = (__bf16)a.x;  o[1] = (__bf16)a.y;  o[2] = (__bf16)a.z;  o[3] = (__bf16)a.w;
    o[4] = (__bf16)b2.x; o[5] = (__bf16)b2.y; o[6] = (__bf16)b2.z; o[7] = (__bf16)b2.w;
    ((bf16x8*)wout2)[i] = o;
  }
}

// ---------------- GEMM 128-tile: C[M,N] = A[M,K] @ W[N,K]^T (+ epilogue) ----------------
// Pinned form: single-buffer 2-barrier, 32KB LDS.
// ROUND-25: EPI_QKV_VT — qkv GEMM writes Q/K linear; V tiles (bn>=2048,
// tile-aligned) are written DIRECTLY TRANSPOSED into vt (resid param), one
// 8B store per 4-row acc group; vtrans kernel eliminated (nothing else read
// qkv's V third). Per d-column a block emits 128 consecutive n's -> L2
// write-combines to full sectors.
enum { EPI_NONE = 0, EPI_BIAS_RES_BF16OUT = 1, EPI_BIAS_GELU = 2, EPI_BIAS_RESBF16_F32OUT = 3,
       EPI_QKV_VT = 4 };

template<int EPI, int NI>
__global__ void __launch_bounds__(256, 2) gemm_bt(
    const obf* __restrict__ A, const obf* __restrict__ Bw,
    void* __restrict__ Cout, const float* __restrict__ bias,
    const void* __restrict__ resid, int M, int N, int K)
{
  __shared__ __align__(16) char As[128 * 64 * 2];
  __shared__ __align__(16) char Bs[NI * 32 * 64 * 2];
  const int tid = threadIdx.x;
  const int lane = tid & 63;
  const int w = tid >> 6, wr = w >> 1, wc = w & 1;
  const int bm = blockIdx.y * 128, bn = blockIdx.x * (NI * 32);
  const size_t lda = (size_t)K * 2;

  f32x4 acc[4][NI];
  #pragma unroll
  for (int i = 0; i < 4; i++)
    #pragma unroll
    for (int j = 0; j < NI; j++) {
      acc[i][j][0] = 0.f; acc[i][j][1] = 0.f; acc[i][j][2] = 0.f; acc[i][j][3] = 0.f;
    }

  for (int k0 = 0; k0 < K; k0 += 64) {
    #pragma unroll
    for (int i = 0; i < 4; i++) {
      const int ci = tid + 256 * i;
      const int r = ci >> 3;
      const int gb = ((ci & 7) * 16) ^ ((r & 7) << 4);
      gload_lds16((const char*)A + (size_t)(bm + r) * lda + (size_t)k0 * 2 + gb, As + ci * 16);
    }
    #pragma unroll
    for (int i = 0; i < NI; i++) {
      const int ci = tid + 256 * i;
      const int r = ci >> 3;
      const int gb = ((ci & 7) * 16) ^ ((r & 7) << 4);
      gload_lds16((const char*)Bw + (size_t)(bn + r) * lda + (size_t)k0 * 2 + gb, Bs + ci * 16);
    }
    __syncthreads();

    bf16x8 af[4][2], bfr[NI][2];
    #pragma unroll
    for (int mi = 0; mi < 4; mi++) {
      const int r = wr * 64 + mi * 16 + (lane & 15);
      #pragma unroll
      for (int ks = 0; ks < 2; ks++) {
        const int cb = ks * 64 + ((lane >> 4) * 16);
        af[mi][ks] = *(const bf16x8*)(As + r * 128 + (cb ^ ((r & 7) << 4)));
      }
    }
    #pragma unroll
    for (int ni = 0; ni < NI; ni++) {
      const int r = wc * (NI * 16) + ni * 16 + (lane & 15);
      #pragma unroll
      for (int ks = 0; ks < 2; ks++) {
        const int cb = ks * 64 + ((lane >> 4) * 16);
        bfr[ni][ks] = *(const bf16x8*)(Bs + r * 128 + (cb ^ ((r & 7) << 4)));
      }
    }
    #pragma unroll
    for (int ks = 0; ks < 2; ks++)
      #pragma unroll
      for (int mi = 0; mi < 4; mi++)
        #pragma unroll
        for (int ni = 0; ni < NI; ni++)
          acc[mi][ni] = __builtin_amdgcn_mfma_f32_16x16x32_bf16(af[mi][ks], bfr[ni][ks], acc[mi][ni], 0, 0, 0);
    __syncthreads();
  }

  if (EPI == EPI_QKV_VT && bn >= 2048) {
    // V tile: write transposed into vt[b][h][d][n] (resid = vt base).
    obf* vt = (obf*)resid;
    #pragma unroll
    for (int mi = 0; mi < 4; mi++) {
      #pragma unroll
      for (int ni = 0; ni < NI; ni++) {
        const int col = bn + wc * (NI * 16) + ni * 16 + (lane & 15) - 2048;
        const int hh = col >> 6, d = col & 63;
        const int row0 = bm + wr * 64 + mi * 16 + ((lane >> 4) << 2);
        const int bb = row0 >> 11, n0 = row0 & 2047;
        obf tmp[4];
        #pragma unroll
        for (int r = 0; r < 4; r++) tmp[r] = __float2bfloat16(acc[mi][ni][r]);
        *(uint2*)(vt + ((size_t)(bb * 16 + hh) * 64 + d) * 2048 + n0) = *(uint2*)tmp;
      }
    }
    return;
  }

  #pragma unroll
  for (int mi = 0; mi < 4; mi++) {
    #pragma unroll
    for (int ni = 0; ni < NI; ni++) {
      const int col = bn + wc * (NI * 16) + ni * 16 + (lane & 15);
      float bv = 0.f;
      if (EPI != EPI_NONE && EPI != EPI_QKV_VT) bv = bias[col];
      #pragma unroll
      for (int r = 0; r < 4; r++) {
        const int row = bm + wr * 64 + mi * 16 + ((lane >> 4) << 2) + r;
        const float vacc = acc[mi][ni][r];
        const size_t idx = (size_t)row * N + col;
        if (EPI == EPI_NONE || EPI == EPI_QKV_VT) {
          ((obf*)Cout)[idx] = __float2bfloat16(vacc);
        } else if (EPI == EPI_BIAS_RES_BF16OUT) {
          const float x0 = ((const float*)resid)[idx];
          ((obf*)Cout)[idx] = __float2bfloat16(vacc + bv + x0);
        } else if (EPI == EPI_BIAS_GELU) {
          const float u = vacc + bv;
          const float e = exp2f(-2.30218709f * (u + 0.044715f * u * u * u));
          ((obf*)Cout)[idx] = __float2bfloat16(u / (1.f + e));
        } else {   // EPI_BIAS_RESBF16_F32OUT
          const float x0 = __bfloat162float(((const obf*)resid)[idx]);
          ((float*)Cout)[idx] = vacc + bv + x0;
        }
      }
    }
  }
}

// ---------------- Flash attention fwd ----------------
// Pinned form (r16/r21): KV=64, 8 waves / 512 threads, Q-tile 128, no-max
// softmax, XCD swizzle, double-buffered Ks/Vs with ONE barrier per tile,
// T14 reg prefetch. LDS 48KB. V read from vt.
__global__ void __launch_bounds__(512, 2) attn_kernel(
    const obf* __restrict__ qkv_, const obf* __restrict__ vt_, obf* __restrict__ ao)
{
  const __bf16* qkv = (const __bf16*)qkv_;
  const __bf16* vt  = (const __bf16*)vt_;
  const int bid = blockIdx.x;            // 0..511
  const int xcd = bid & 7, idx = bid >> 3;
  const int bh = xcd * 4 + (idx >> 4);   // 4 bh per XCD (K/V L2-resident)
  const int q0 = (idx & 15) * 128;
  const int b = bh >> 4, h = bh & 15;
  const int tid = threadIdx.x, lane = tid & 63, w = tid >> 6;   // w 0..7
  const int l15 = lane & 15, hi = lane >> 4;

  __shared__ __align__(16) char Ks[2][64 * 128];   // [kv=64][d=64]*2B, swizzled
  __shared__ __align__(16) char Vs[2][64 * 128];   // [d=64][kv=64]*2B, swizzled
  __shared__ __align__(16) char Ps[8 * 16 * 128];  // per-wave [16 q][64 kv]*2B, swz

  bf16x8 qf[2];
  {
    const int qrow = q0 + w * 16 + l15;
    #pragma unroll
    for (int ks = 0; ks < 2; ks++)
      qf[ks] = *(const bf16x8*)(qkv + ((size_t)(b * 2048 + qrow)) * 3072 + h * 64 + ks * 32 + hi * 8);
  }

  f32x4 o[4];
  #pragma unroll
  for (int j = 0; j < 4; j++) { o[j][0]=0.f; o[j][1]=0.f; o[j][2]=0.f; o[j][3]=0.f; }
  float lrow[4] = { 0.f, 0.f, 0.f, 0.f };

  const float kfac = 0.125f * 1.44269504089f;  // scale * log2(e)

  const int kr = tid >> 3, kc = (tid & 7) * 8;   // staging coords (1 chunk/thread)
  const int kcb = (tid & 7) * 16;
  const int kswz = kcb ^ ((kr & 7) << 4);

  bf16x8 pk, pv;
  pk = *(const bf16x8*)(qkv + ((size_t)(b * 2048 + kr)) * 3072 + 1024 + h * 64 + kc);
  pv = *(const bf16x8*)(vt + ((size_t)bh * 64 + kr) * 2048 + kc);
  *(bf16x8*)(Ks[0] + kr * 128 + kswz) = pk;
  *(bf16x8*)(Vs[0] + kr * 128 + kswz) = pv;
  __syncthreads();

  for (int kt = 0; kt < 2048; kt += 64) {
    const int cur = (kt >> 6) & 1;
    if (kt + 64 < 2048) {
      pk = *(const bf16x8*)(qkv + ((size_t)(b * 2048 + kt + 64 + kr)) * 3072 + 1024 + h * 64 + kc);
      pv = *(const bf16x8*)(vt + ((size_t)bh * 64 + kr) * 2048 + kt + 64 + kc);
    }

    f32x4 s[4];
    #pragma unroll
    for (int j = 0; j < 4; j++) { s[j][0]=0.f; s[j][1]=0.f; s[j][2]=0.f; s[j][3]=0.f; }
    #pragma unroll
    for (int ni = 0; ni < 4; ni++) {
      const int r = ni * 16 + l15;
      const bf16x8 kf0 = *(const bf16x8*)(Ks[cur] + r * 128 + ((hi * 16) ^ ((r & 7) << 4)));
      const bf16x8 kf1 = *(const bf16x8*)(Ks[cur] + r * 128 + ((64 + hi * 16) ^ ((r & 7) << 4)));
      s[ni] = __builtin_amdgcn_mfma_f32_16x16x32_bf16(qf[0], kf0, s[ni], 0, 0, 0);
      s[ni] = __builtin_amdgcn_mfma_f32_16x16x32_bf16(qf[1], kf1, s[ni], 0, 0, 0);
    }

    #pragma unroll
    for (int r = 0; r < 4; r++) {
      const int qrl = (hi << 2) + r;
      char* psrow = Ps + w * 2048 + qrl * 128;
      float psum = 0.f;
      #pragma unroll
      for (int ni = 0; ni < 4; ni++) {
        const float p = exp2f(s[ni][r] * kfac);
        psum += p;
        *(__bf16*)(psrow + (((ni * 16 + l15) * 2) ^ ((qrl & 7) << 4))) = (__bf16)p;
      }
      lrow[r] += psum;
    }

    #pragma unroll
    for (int ks = 0; ks < 2; ks++) {
      const int rr = l15;
      const bf16x8 pa = *(const bf16x8*)(Ps + w * 2048 + rr * 128 + (((ks * 32 + hi * 8) * 2) ^ ((rr & 7) << 4)));
      #pragma unroll
      for (int df = 0; df < 4; df++) {
        const int dr = df * 16 + l15;
        const int cb = (ks * 32 + hi * 8) * 2;
        const bf16x8 vb = *(const bf16x8*)(Vs[cur] + dr * 128 + (cb ^ ((dr & 7) << 4)));
        o[df] = __builtin_amdgcn_mfma_f32_16x16x32_bf16(pa, vb, o[df], 0, 0, 0);
      }
    }

    if (kt + 64 < 2048) {
      *(bf16x8*)(Ks[cur ^ 1] + kr * 128 + kswz) = pk;
      *(bf16x8*)(Vs[cur ^ 1] + kr * 128 + kswz) = pv;
    }
    __syncthreads();
  }

  #pragma unroll
  for (int r = 0; r < 4; r++) {
    lrow[r] += __shfl_xor(lrow[r], 1);
    lrow[r] += __shfl_xor(lrow[r], 2);
    lrow[r] += __shfl_xor(lrow[r], 4);
    lrow[r] += __shfl_xor(lrow[r], 8);
  }
  #pragma unroll
  for (int r = 0; r < 4; r++) {
    const float inv = 1.f / lrow[r];
    const int qrow = q0 + w * 16 + (hi << 2) + r;
    #pragma unroll
    for (int df = 0; df < 4; df++) {
      const int col = h * 64 + df * 16 + l15;
      ao[((size_t)(b * 2048 + qrow)) * 1024 + col] = __float2bfloat16(o[df][r] * inv);
    }
  }
}

// ---------------- launch ----------------
// ROUND-25 ws layout (64 MB):
//   [ 0, 8M)  x2   bf16 (written d3, read d4 + d6)
//   [ 8,16M)  vt (d1 write via qkv GEMM, d2 read)  ->  wb_w2 (d4 write, d6 read)
//   [16,24M)  h    (d0 write, d1 read; d4 write, d5 read)
//   [24,48M)  qkv  (d1 write, d2 read)  -> part of m1
//   [48,56M)  ao   (d2 write, d3 read)  -> part of m1 (m1 = [24,56M), d5->d6)
//   [56,62M)  wb_qkv (d0, d1) \ -> wb_w1 [56,64M) (d4 write, d5 read)
//   [62,64M)  wb_proj (d0, d3)/
// 7 dispatches (vtrans folded into the qkv GEMM epilogue).
extern "C" void kernel_launch(void* const* d_in, const int* in_sizes, int n_in,
                              void* d_out, int out_size, void* d_ws, size_t ws_size,
                              hipStream_t stream) {
  const float* x      = (const float*)d_in[0];
  const float* ln1_g  = (const float*)d_in[1];
  const float* ln1_b  = (const float*)d_in[2];
  const float* qkv_w  = (const float*)d_in[3];
  const float* proj_w = (const float*)d_in[4];
  const float* proj_b = (const float*)d_in[5];
  const float* ln2_g  = (const float*)d_in[6];
  const float* ln2_b  = (const float*)d_in[7];
  const float* w1     = (const float*)d_in[8];
  const float* b1     = (const float*)d_in[9];
  const float* w2     = (const float*)d_in[10];
  const float* b2     = (const float*)d_in[11];
  float* out = (float*)d_out;                       // reference output dtype: float32

  char* ws = (char*)d_ws;
  obf*   x2      = (obf*)ws;                       //  8 MB bf16
  obf*   vt      = (obf*)(ws + ( 8u << 20));       //  8 MB (later wb_w2)
  __bf16* wb_w2  = (__bf16*)(ws + ( 8u << 20));
  obf*   h       = (obf*)(ws + (16u << 20));       //  8 MB
  obf*   qkv     = (obf*)(ws + (24u << 20));       // 24 MB (V third unused/linear-skipped)
  obf*   ao      = (obf*)(ws + (48u << 20));       //  8 MB
  obf*   m1      = (obf*)(ws + (24u << 20));       // 32 MB (overlays qkv+ao)
  __bf16* wb_qkv  = (__bf16*)(ws + (56u << 20));   //  6 MB
  __bf16* wb_proj = (__bf16*)(ws + (62u << 20));   //  2 MB
  __bf16* wb_w1   = (__bf16*)(ws + (56u << 20));   //  8 MB (overwrites qkv/proj wb)

  const int M = 4096;

  // 0. merged: LN1 (x -> h) + f2b(qkv_w) + f2b(proj_w)
  ln_f2b2_kernel<false><<<M + 1536 + 512, 256, 0, stream>>>(
      x, ln1_g, ln1_b, h,
      qkv_w, wb_qkv, 3072 * 1024 / 8, 1536,
      proj_w, wb_proj, 1024 * 1024 / 8, M);
  // 1. qkv = h @ qkv_w^T   (Q/K linear; V written transposed into vt)
  gemm_bt<EPI_QKV_VT, 4><<<dim3(3072 / 128, M / 128), 256, 0, stream>>>(
      h, (const obf*)wb_qkv, qkv, nullptr, vt, M, 3072, 1024);
  // 2. attention -> ao
  attn_kernel<<<512, 512, 0, stream>>>(qkv, vt, ao);
  // 3. x2 = bf16(x + ao @ proj_w^T + proj_b)
  gemm_bt<EPI_BIAS_RES_BF16OUT, 2><<<dim3(1024 / 64, M / 128), 256, 0, stream>>>(
      ao, (const obf*)wb_proj, x2, proj_b, x, M, 1024, 1024);
  // 4. merged: LN2 (bf16 x2 -> h) + f2b(w1) + f2b(w2)   (vt dead; wb_qkv/proj dead)
  ln_f2b2_kernel<true><<<M + 2048 + 2048, 256, 0, stream>>>(
      x2, ln2_g, ln2_b, h,
      w1, wb_w1, 4096 * 1024 / 8, 2048,
      w2, wb_w2, 4096 * 1024 / 8, M);
  // 5. m1 = gelu(h @ w1^T + b1)   (tanh-GELU)
  gemm_bt<EPI_BIAS_GELU, 4><<<dim3(4096 / 128, M / 128), 256, 0, stream>>>(
      h, (const obf*)wb_w1, m1, b1, nullptr, M, 4096, 1024);
  // 6. out = f32(x2 + m1 @ w2^T + b2) -> d_out
  gemm_bt<EPI_BIAS_RESBF16_F32OUT, 2><<<dim3(1024 / 64, M / 128), 256, 0, stream>>>(
      m1, (const obf*)wb_w2, out, b2, x2, M, 1024, 4096);
}

// Round 26
// 229.393 us; speedup vs baseline: 1.0913x; 1.0030x over previous
//
#include <hip/hip_runtime.h>
#include <hip/hip_bf16.h>

typedef __hip_bfloat16 obf;
typedef __attribute__((ext_vector_type(8))) __bf16 bf16x8;
typedef __attribute__((ext_vector_type(4))) float f32x4;

#define DEVINL __device__ __forceinline__

DEVINL void gload_lds16(const void* g, void* l) {
  __builtin_amdgcn_global_load_lds((const __attribute__((address_space(1))) void*)g,
                                   (__attribute__((address_space(3))) void*)l,
                                   16, 0, 0);
}

DEVINL float bf2f(unsigned short h) {
  union { unsigned int u; float f; } c; c.u = ((unsigned)h) << 16; return c.f;
}

// ------- merged LayerNorm + two f2b segments (independent work, one dispatch) -------
template<bool INBF16>
__global__ void __launch_bounds__(256) ln_f2b2_kernel(
    const void* __restrict__ xin, const float* __restrict__ g, const float* __restrict__ b,
    obf* __restrict__ lnout,
    const float* __restrict__ win1, __bf16* __restrict__ wout1, int n8_1, int nb1,
    const float* __restrict__ win2, __bf16* __restrict__ wout2, int n8_2,
    int nln)
{
  __shared__ float red[8];
  const int t = threadIdx.x;
  const int bx = blockIdx.x;
  if (bx < nln) {
    const int row = bx;
    const int lane = t & 63, w = t >> 6;
    float v[4];
    if (INBF16) {
      ushort4 u = ((const ushort4*)xin)[(size_t)row * 256 + t];
      v[0] = bf2f(u.x); v[1] = bf2f(u.y); v[2] = bf2f(u.z); v[3] = bf2f(u.w);
    } else {
      float4 f = ((const float4*)xin)[(size_t)row * 256 + t];
      v[0] = f.x; v[1] = f.y; v[2] = f.z; v[3] = f.w;
    }
    float s1 = v[0] + v[1] + v[2] + v[3];
    float s2 = v[0]*v[0] + v[1]*v[1] + v[2]*v[2] + v[3]*v[3];
    #pragma unroll
    for (int off = 32; off >= 1; off >>= 1) {
      s1 += __shfl_xor(s1, off);
      s2 += __shfl_xor(s2, off);
    }
    if (lane == 0) { red[w] = s1; red[4 + w] = s2; }
    __syncthreads();
    s1 = red[0] + red[1] + red[2] + red[3];
    s2 = red[4] + red[5] + red[6] + red[7];
    const float mu = s1 * (1.f / 1024.f);
    const float var = s2 * (1.f / 1024.f) - mu * mu;
    const float rs = rsqrtf(var + 1e-5f);
    const float4 gv = ((const float4*)g)[t];
    const float4 bv = ((const float4*)b)[t];
    obf* op = lnout + (size_t)row * 1024 + t * 4;
    op[0] = __float2bfloat16((v[0] - mu) * rs * gv.x + bv.x);
    op[1] = __float2bfloat16((v[1] - mu) * rs * gv.y + bv.y);
    op[2] = __float2bfloat16((v[2] - mu) * rs * gv.z + bv.z);
    op[3] = __float2bfloat16((v[3] - mu) * rs * gv.w + bv.w);
  } else if (bx < nln + nb1) {
    const int i = (bx - nln) * 256 + t;
    if (i >= n8_1) return;
    const float4 a = ((const float4*)win1)[i * 2];
    const float4 b2 = ((const float4*)win1)[i * 2 + 1];
    bf16x8 o;
    o[0] = (__bf16)a.x;  o[1] = (__bf16)a.y;  o[2] = (__bf16)a.z;  o[3] = (__bf16)a.w;
    o[4] = (__bf16)b2.x; o[5] = (__bf16)b2.y; o[6] = (__bf16)b2.z; o[7] = (__bf16)b2.w;
    ((bf16x8*)wout1)[i] = o;
  } else {
    const int i = (bx - nln - nb1) * 256 + t;
    if (i >= n8_2) return;
    const float4 a = ((const float4*)win2)[i * 2];
    const float4 b2 = ((const float4*)win2)[i * 2 + 1];
    bf16x8 o;
    o[0] = (__bf16)a.x;  o[1] = (__bf16)a.y;  o[2] = (__bf16)a.z;  o[3] = (__bf16)a.w;
    o[4] = (__bf16)b2.x; o[5] = (__bf16)b2.y; o[6] = (__bf16)b2.z; o[7] = (__bf16)b2.w;
    ((bf16x8*)wout2)[i] = o;
  }
}

// ---------------- GEMM 128-tile: C[M,N] = A[M,K] @ W[N,K]^T (+ epilogue) ----------------
// Pinned form: single-buffer 2-barrier, 32KB LDS. EPI_QKV_VT writes V tiles
// transposed into vt (validated r25).
enum { EPI_NONE = 0, EPI_BIAS_RES_BF16OUT = 1, EPI_BIAS_GELU = 2, EPI_BIAS_RESBF16_F32OUT = 3,
       EPI_QKV_VT = 4 };

template<int EPI, int NI>
__global__ void __launch_bounds__(256, 2) gemm_bt(
    const obf* __restrict__ A, const obf* __restrict__ Bw,
    void* __restrict__ Cout, const float* __restrict__ bias,
    const void* __restrict__ resid, int M, int N, int K)
{
  __shared__ __align__(16) char As[128 * 64 * 2];
  __shared__ __align__(16) char Bs[NI * 32 * 64 * 2];
  const int tid = threadIdx.x;
  const int lane = tid & 63;
  const int w = tid >> 6, wr = w >> 1, wc = w & 1;
  const int bm = blockIdx.y * 128, bn = blockIdx.x * (NI * 32);
  const size_t lda = (size_t)K * 2;

  f32x4 acc[4][NI];
  #pragma unroll
  for (int i = 0; i < 4; i++)
    #pragma unroll
    for (int j = 0; j < NI; j++) {
      acc[i][j][0] = 0.f; acc[i][j][1] = 0.f; acc[i][j][2] = 0.f; acc[i][j][3] = 0.f;
    }

  for (int k0 = 0; k0 < K; k0 += 64) {
    #pragma unroll
    for (int i = 0; i < 4; i++) {
      const int ci = tid + 256 * i;
      const int r = ci >> 3;
      const int gb = ((ci & 7) * 16) ^ ((r & 7) << 4);
      gload_lds16((const char*)A + (size_t)(bm + r) * lda + (size_t)k0 * 2 + gb, As + ci * 16);
    }
    #pragma unroll
    for (int i = 0; i < NI; i++) {
      const int ci = tid + 256 * i;
      const int r = ci >> 3;
      const int gb = ((ci & 7) * 16) ^ ((r & 7) << 4);
      gload_lds16((const char*)Bw + (size_t)(bn + r) * lda + (size_t)k0 * 2 + gb, Bs + ci * 16);
    }
    __syncthreads();

    bf16x8 af[4][2], bfr[NI][2];
    #pragma unroll
    for (int mi = 0; mi < 4; mi++) {
      const int r = wr * 64 + mi * 16 + (lane & 15);
      #pragma unroll
      for (int ks = 0; ks < 2; ks++) {
        const int cb = ks * 64 + ((lane >> 4) * 16);
        af[mi][ks] = *(const bf16x8*)(As + r * 128 + (cb ^ ((r & 7) << 4)));
      }
    }
    #pragma unroll
    for (int ni = 0; ni < NI; ni++) {
      const int r = wc * (NI * 16) + ni * 16 + (lane & 15);
      #pragma unroll
      for (int ks = 0; ks < 2; ks++) {
        const int cb = ks * 64 + ((lane >> 4) * 16);
        bfr[ni][ks] = *(const bf16x8*)(Bs + r * 128 + (cb ^ ((r & 7) << 4)));
      }
    }
    #pragma unroll
    for (int ks = 0; ks < 2; ks++)
      #pragma unroll
      for (int mi = 0; mi < 4; mi++)
        #pragma unroll
        for (int ni = 0; ni < NI; ni++)
          acc[mi][ni] = __builtin_amdgcn_mfma_f32_16x16x32_bf16(af[mi][ks], bfr[ni][ks], acc[mi][ni], 0, 0, 0);
    __syncthreads();
  }

  if (EPI == EPI_QKV_VT && bn >= 2048) {
    obf* vt = (obf*)resid;
    #pragma unroll
    for (int mi = 0; mi < 4; mi++) {
      #pragma unroll
      for (int ni = 0; ni < NI; ni++) {
        const int col = bn + wc * (NI * 16) + ni * 16 + (lane & 15) - 2048;
        const int hh = col >> 6, d = col & 63;
        const int row0 = bm + wr * 64 + mi * 16 + ((lane >> 4) << 2);
        const int bb = row0 >> 11, n0 = row0 & 2047;
        obf tmp[4];
        #pragma unroll
        for (int r = 0; r < 4; r++) tmp[r] = __float2bfloat16(acc[mi][ni][r]);
        *(uint2*)(vt + ((size_t)(bb * 16 + hh) * 64 + d) * 2048 + n0) = *(uint2*)tmp;
      }
    }
    return;
  }

  #pragma unroll
  for (int mi = 0; mi < 4; mi++) {
    #pragma unroll
    for (int ni = 0; ni < NI; ni++) {
      const int col = bn + wc * (NI * 16) + ni * 16 + (lane & 15);
      float bv = 0.f;
      if (EPI != EPI_NONE && EPI != EPI_QKV_VT) bv = bias[col];
      #pragma unroll
      for (int r = 0; r < 4; r++) {
        const int row = bm + wr * 64 + mi * 16 + ((lane >> 4) << 2) + r;
        const float vacc = acc[mi][ni][r];
        const size_t idx = (size_t)row * N + col;
        if (EPI == EPI_NONE || EPI == EPI_QKV_VT) {
          ((obf*)Cout)[idx] = __float2bfloat16(vacc);
        } else if (EPI == EPI_BIAS_RES_BF16OUT) {
          const float x0 = ((const float*)resid)[idx];
          ((obf*)Cout)[idx] = __float2bfloat16(vacc + bv + x0);
        } else if (EPI == EPI_BIAS_GELU) {
          const float u = vacc + bv;
          const float e = exp2f(-2.30218709f * (u + 0.044715f * u * u * u));
          ((obf*)Cout)[idx] = __float2bfloat16(u / (1.f + e));
        } else {   // EPI_BIAS_RESBF16_F32OUT
          const float x0 = __bfloat162float(((const obf*)resid)[idx]);
          ((float*)Cout)[idx] = vacc + bv + x0;
        }
      }
    }
  }
}

// ---------------- Flash attention fwd ----------------
// Pinned form + ROUND-26: T5 s_setprio(1) around the QK^T and PV MFMA
// clusters (catalog m191: +4-7% on attn with wave role-diversity; our 8
// independent waves/block x 2 blocks/CU at different kv phases qualify).
__global__ void __launch_bounds__(512, 2) attn_kernel(
    const obf* __restrict__ qkv_, const obf* __restrict__ vt_, obf* __restrict__ ao)
{
  const __bf16* qkv = (const __bf16*)qkv_;
  const __bf16* vt  = (const __bf16*)vt_;
  const int bid = blockIdx.x;            // 0..511
  const int xcd = bid & 7, idx = bid >> 3;
  const int bh = xcd * 4 + (idx >> 4);   // 4 bh per XCD (K/V L2-resident)
  const int q0 = (idx & 15) * 128;
  const int b = bh >> 4, h = bh & 15;
  const int tid = threadIdx.x, lane = tid & 63, w = tid >> 6;   // w 0..7
  const int l15 = lane & 15, hi = lane >> 4;

  __shared__ __align__(16) char Ks[2][64 * 128];   // [kv=64][d=64]*2B, swizzled
  __shared__ __align__(16) char Vs[2][64 * 128];   // [d=64][kv=64]*2B, swizzled
  __shared__ __align__(16) char Ps[8 * 16 * 128];  // per-wave [16 q][64 kv]*2B, swz

  bf16x8 qf[2];
  {
    const int qrow = q0 + w * 16 + l15;
    #pragma unroll
    for (int ks = 0; ks < 2; ks++)
      qf[ks] = *(const bf16x8*)(qkv + ((size_t)(b * 2048 + qrow)) * 3072 + h * 64 + ks * 32 + hi * 8);
  }

  f32x4 o[4];
  #pragma unroll
  for (int j = 0; j < 4; j++) { o[j][0]=0.f; o[j][1]=0.f; o[j][2]=0.f; o[j][3]=0.f; }
  float lrow[4] = { 0.f, 0.f, 0.f, 0.f };

  const float kfac = 0.125f * 1.44269504089f;  // scale * log2(e)

  const int kr = tid >> 3, kc = (tid & 7) * 8;   // staging coords (1 chunk/thread)
  const int kcb = (tid & 7) * 16;
  const int kswz = kcb ^ ((kr & 7) << 4);

  bf16x8 pk, pv;
  pk = *(const bf16x8*)(qkv + ((size_t)(b * 2048 + kr)) * 3072 + 1024 + h * 64 + kc);
  pv = *(const bf16x8*)(vt + ((size_t)bh * 64 + kr) * 2048 + kc);
  *(bf16x8*)(Ks[0] + kr * 128 + kswz) = pk;
  *(bf16x8*)(Vs[0] + kr * 128 + kswz) = pv;
  __syncthreads();

  for (int kt = 0; kt < 2048; kt += 64) {
    const int cur = (kt >> 6) & 1;
    if (kt + 64 < 2048) {
      pk = *(const bf16x8*)(qkv + ((size_t)(b * 2048 + kt + 64 + kr)) * 3072 + 1024 + h * 64 + kc);
      pv = *(const bf16x8*)(vt + ((size_t)bh * 64 + kr) * 2048 + kt + 64 + kc);
    }

    f32x4 s[4];
    #pragma unroll
    for (int j = 0; j < 4; j++) { s[j][0]=0.f; s[j][1]=0.f; s[j][2]=0.f; s[j][3]=0.f; }
    __builtin_amdgcn_s_setprio(1);
    #pragma unroll
    for (int ni = 0; ni < 4; ni++) {
      const int r = ni * 16 + l15;
      const bf16x8 kf0 = *(const bf16x8*)(Ks[cur] + r * 128 + ((hi * 16) ^ ((r & 7) << 4)));
      const bf16x8 kf1 = *(const bf16x8*)(Ks[cur] + r * 128 + ((64 + hi * 16) ^ ((r & 7) << 4)));
      s[ni] = __builtin_amdgcn_mfma_f32_16x16x32_bf16(qf[0], kf0, s[ni], 0, 0, 0);
      s[ni] = __builtin_amdgcn_mfma_f32_16x16x32_bf16(qf[1], kf1, s[ni], 0, 0, 0);
    }
    __builtin_amdgcn_s_setprio(0);

    #pragma unroll
    for (int r = 0; r < 4; r++) {
      const int qrl = (hi << 2) + r;
      char* psrow = Ps + w * 2048 + qrl * 128;
      float psum = 0.f;
      #pragma unroll
      for (int ni = 0; ni < 4; ni++) {
        const float p = exp2f(s[ni][r] * kfac);
        psum += p;
        *(__bf16*)(psrow + (((ni * 16 + l15) * 2) ^ ((qrl & 7) << 4))) = (__bf16)p;
      }
      lrow[r] += psum;
    }

    __builtin_amdgcn_s_setprio(1);
    #pragma unroll
    for (int ks = 0; ks < 2; ks++) {
      const int rr = l15;
      const bf16x8 pa = *(const bf16x8*)(Ps + w * 2048 + rr * 128 + (((ks * 32 + hi * 8) * 2) ^ ((rr & 7) << 4)));
      #pragma unroll
      for (int df = 0; df < 4; df++) {
        const int dr = df * 16 + l15;
        const int cb = (ks * 32 + hi * 8) * 2;
        const bf16x8 vb = *(const bf16x8*)(Vs[cur] + dr * 128 + (cb ^ ((dr & 7) << 4)));
        o[df] = __builtin_amdgcn_mfma_f32_16x16x32_bf16(pa, vb, o[df], 0, 0, 0);
      }
    }
    __builtin_amdgcn_s_setprio(0);

    if (kt + 64 < 2048) {
      *(bf16x8*)(Ks[cur ^ 1] + kr * 128 + kswz) = pk;
      *(bf16x8*)(Vs[cur ^ 1] + kr * 128 + kswz) = pv;
    }
    __syncthreads();
  }

  #pragma unroll
  for (int r = 0; r < 4; r++) {
    lrow[r] += __shfl_xor(lrow[r], 1);
    lrow[r] += __shfl_xor(lrow[r], 2);
    lrow[r] += __shfl_xor(lrow[r], 4);
    lrow[r] += __shfl_xor(lrow[r], 8);
  }
  #pragma unroll
  for (int r = 0; r < 4; r++) {
    const float inv = 1.f / lrow[r];
    const int qrow = q0 + w * 16 + (hi << 2) + r;
    #pragma unroll
    for (int df = 0; df < 4; df++) {
      const int col = h * 64 + df * 16 + l15;
      ao[((size_t)(b * 2048 + qrow)) * 1024 + col] = __float2bfloat16(o[df][r] * inv);
    }
  }
}

// ---------------- launch ----------------
// ws layout (64 MB):
//   [ 0, 8M)  x2   bf16 (written d3, read d4 + d6)
//   [ 8,16M)  vt (d1 write via qkv GEMM, d2 read)  ->  wb_w2 (d4 write, d6 read)
//   [16,24M)  h    (d0 write, d1 read; d4 write, d5 read)
//   [24,48M)  qkv  (d1 write, d2 read)  -> part of m1
//   [48,56M)  ao   (d2 write, d3 read)  -> part of m1 (m1 = [24,56M), d5->d6)
//   [56,62M)  wb_qkv (d0, d1) \ -> wb_w1 [56,64M) (d4 write, d5 read)
//   [62,64M)  wb_proj (d0, d3)/
// 7 dispatches.
extern "C" void kernel_launch(void* const* d_in, const int* in_sizes, int n_in,
                              void* d_out, int out_size, void* d_ws, size_t ws_size,
                              hipStream_t stream) {
  const float* x      = (const float*)d_in[0];
  const float* ln1_g  = (const float*)d_in[1];
  const float* ln1_b  = (const float*)d_in[2];
  const float* qkv_w  = (const float*)d_in[3];
  const float* proj_w = (const float*)d_in[4];
  const float* proj_b = (const float*)d_in[5];
  const float* ln2_g  = (const float*)d_in[6];
  const float* ln2_b  = (const float*)d_in[7];
  const float* w1     = (const float*)d_in[8];
  const float* b1     = (const float*)d_in[9];
  const float* w2     = (const float*)d_in[10];
  const float* b2     = (const float*)d_in[11];
  float* out = (float*)d_out;                       // reference output dtype: float32

  char* ws = (char*)d_ws;
  obf*   x2      = (obf*)ws;                       //  8 MB bf16
  obf*   vt      = (obf*)(ws + ( 8u << 20));       //  8 MB (later wb_w2)
  __bf16* wb_w2  = (__bf16*)(ws + ( 8u << 20));
  obf*   h       = (obf*)(ws + (16u << 20));       //  8 MB
  obf*   qkv     = (obf*)(ws + (24u << 20));       // 24 MB
  obf*   ao      = (obf*)(ws + (48u << 20));       //  8 MB
  obf*   m1      = (obf*)(ws + (24u << 20));       // 32 MB (overlays qkv+ao)
  __bf16* wb_qkv  = (__bf16*)(ws + (56u << 20));   //  6 MB
  __bf16* wb_proj = (__bf16*)(ws + (62u << 20));   //  2 MB
  __bf16* wb_w1   = (__bf16*)(ws + (56u << 20));   //  8 MB (overwrites qkv/proj wb)

  const int M = 4096;

  // 0. merged: LN1 (x -> h) + f2b(qkv_w) + f2b(proj_w)
  ln_f2b2_kernel<false><<<M + 1536 + 512, 256, 0, stream>>>(
      x, ln1_g, ln1_b, h,
      qkv_w, wb_qkv, 3072 * 1024 / 8, 1536,
      proj_w, wb_proj, 1024 * 1024 / 8, M);
  // 1. qkv = h @ qkv_w^T   (Q/K linear; V written transposed into vt)
  gemm_bt<EPI_QKV_VT, 4><<<dim3(3072 / 128, M / 128), 256, 0, stream>>>(
      h, (const obf*)wb_qkv, qkv, nullptr, vt, M, 3072, 1024);
  // 2. attention -> ao
  attn_kernel<<<512, 512, 0, stream>>>(qkv, vt, ao);
  // 3. x2 = bf16(x + ao @ proj_w^T + proj_b)
  gemm_bt<EPI_BIAS_RES_BF16OUT, 2><<<dim3(1024 / 64, M / 128), 256, 0, stream>>>(
      ao, (const obf*)wb_proj, x2, proj_b, x, M, 1024, 1024);
  // 4. merged: LN2 (bf16 x2 -> h) + f2b(w1) + f2b(w2)
  ln_f2b2_kernel<true><<<M + 2048 + 2048, 256, 0, stream>>>(
      x2, ln2_g, ln2_b, h,
      w1, wb_w1, 4096 * 1024 / 8, 2048,
      w2, wb_w2, 4096 * 1024 / 8, M);
  // 5. m1 = gelu(h @ w1^T + b1)   (tanh-GELU)
  gemm_bt<EPI_BIAS_GELU, 4><<<dim3(4096 / 128, M / 128), 256, 0, stream>>>(
      h, (const obf*)wb_w1, m1, b1, nullptr, M, 4096, 1024);
  // 6. out = f32(x2 + m1 @ w2^T + b2) -> d_out
  gemm_bt<EPI_BIAS_RESBF16_F32OUT, 2><<<dim3(1024 / 64, M / 128), 256, 0, stream>>>(
      m1, (const obf*)wb_w2, out, b2, x2, M, 1024, 4096);
}